// Round 3
// baseline (8703.875 us; speedup 1.0000x reference)
//
#include <hip/hip_runtime.h>
#include <hip/hip_bf16.h>

// ---------------------------------------------------------------------------
// StandardMRALSTM — round 8: fused per-phase dispatch (gemm+gates in ONE kernel).
//  * R7 post-mortem: in_npz=100.4MB => inputs are fp32 => mode==0 => the BF/MFMA
//    path is DORMANT; active path is gemm_slot_f32 + fp32 gates. R7's neutral
//    delta confirmed. Real budget: 516 sequential dispatches, 12.9us each.
//  * Change: one phase_kernel per tau (768 blocks). Blocks 0..ntot-1 do gemm,
//    arrive via 2-level device-scope counters; blocks 0..255 then spin (tid0,
//    s_sleep backoff) until their seg's partials are published, and run gates.
//  * Cross-XCD within-dispatch dataflow (partials) uses agent-scope relaxed
//    atomics (write-through coherent point, bypass per-XCD L2). All other
//    dataflow stays cross-dispatch (boundary coherence, as before).
//  * Deadlock-free: spinners=256 blocks; __launch_bounds__(256,2) guarantees
//    >=2 blocks/CU => >=512 resident slots => producers always schedulable.
// ---------------------------------------------------------------------------

#define LL 4
#define HH 512
#define TS 128
#define GG 16
#define BB 64
#define FF 64
#define TT 4
#define FIVE_H 2560
#define LBH (LL * BB * HH)

typedef unsigned short u16;
typedef unsigned int u32;
typedef unsigned long long u64;

typedef short bfrag8 __attribute__((ext_vector_type(8)));   // 8 bf16
typedef float facc4 __attribute__((ext_vector_type(4)));    // 4 fp32

#define SG_OFF    64
#define ZALL_OFF  1024
#define ZMASK_OFF 2048
#define C_OFF     4096
#define PING_OFF  (C_OFF + LBH)                       // 135168
#define PART_OFF  (PING_OFF + 2 * LBH)                // 397312
#define PART_SEG  (12 * 4 * HH * BB)                  // 1572864 floats per seg
#define HIST_OFF  (PART_OFF + 2 * PART_SEG)           // 3543040 (u16 region)
// hist: TS*4 * HH * BB u16 = 16777216 u16 = 8388608 floats
#define HFRAG_OFF (HIST_OFF + 8388608)                // 11931648 (u16 region)
#define WFRAG_OFF (HFRAG_OFF + 262144)                // 12193792 (u16 region)
// wfrag: 4 mats * 4 layers * 2560 rows * 512 k u16 = 20971520 u16 (41.9 MB)
#define CNT_OFF   (WFRAG_OFF + 10485760)              // 22679552 (int region)
// counters: 258 taus * 32 ints ([0]=seg0 done,[1]=seg1 done,[2..25]=unit cnts)

__device__ __forceinline__ float bf2f(u16 u) { return __uint_as_float(((u32)u) << 16); }
__device__ __forceinline__ float2 bf2x2(u32 u) {
    float2 r;
    r.x = __uint_as_float(u << 16);
    r.y = __uint_as_float(u & 0xFFFF0000u);
    return r;
}
__device__ __forceinline__ u16 f2bf_rne(float f) {
    u32 x = __float_as_uint(f);
    return (u16)((x + 0x7FFFu + ((x >> 16) & 1u)) >> 16);
}
__device__ __forceinline__ float sigm(float x) { return 1.f / (1.f + expf(-x)); }

__device__ __forceinline__ void st_agent(float* p, float v) {
    __hip_atomic_store(p, v, __ATOMIC_RELAXED, __HIP_MEMORY_SCOPE_AGENT);
}
__device__ __forceinline__ float ld_agent(const float* p) {
    return __hip_atomic_load((float*)p, __ATOMIC_RELAXED, __HIP_MEMORY_SCOPE_AGENT);
}

template <bool BF>
__device__ __forceinline__ float ldv(const void* p, size_t i) {
    return BF ? bf2f(((const u16*)p)[i]) : ((const float*)p)[i];
}

template <bool BF>
__device__ __forceinline__ float dot16(const void* row, const float* xs) {
    float s = 0.f;
    if (BF) {
        const uint4* p = (const uint4*)row;
        uint4 a = p[0], b4 = p[1];
        float2 v;
        v = bf2x2(a.x);  s += v.x * xs[0]  + v.y * xs[1];
        v = bf2x2(a.y);  s += v.x * xs[2]  + v.y * xs[3];
        v = bf2x2(a.z);  s += v.x * xs[4]  + v.y * xs[5];
        v = bf2x2(a.w);  s += v.x * xs[6]  + v.y * xs[7];
        v = bf2x2(b4.x); s += v.x * xs[8]  + v.y * xs[9];
        v = bf2x2(b4.y); s += v.x * xs[10] + v.y * xs[11];
        v = bf2x2(b4.z); s += v.x * xs[12] + v.y * xs[13];
        v = bf2x2(b4.w); s += v.x * xs[14] + v.y * xs[15];
    } else {
        const float4* p = (const float4*)row;
#pragma unroll
        for (int i = 0; i < 4; ++i) {
            float4 v = p[i];
            s += v.x * xs[4 * i] + v.y * xs[4 * i + 1] + v.z * xs[4 * i + 2] + v.w * xs[4 * i + 3];
        }
    }
    return s;
}

// ---- init A ----------------------------------------------------------------
__global__ void initA_kernel(const u16* __restrict__ bnd_raw, float* __restrict__ ws) {
    size_t i = (size_t)blockIdx.x * 256 + threadIdx.x;
    if (i < LBH) ws[C_OFF + i] = 0.f;
    if (i < 512) ws[SG_OFF + i] = 0.f;
    if (i < 258 * 32) ((int*)(ws + CNT_OFF))[i] = 0;
    if (i == 0) {
        int bf = 1;
        for (int j = 0; j < 32; ++j) {
            float v = bf2f(bnd_raw[2 * j]);
            if (!(v >= 0.f && v <= 1.f)) bf = 0;
        }
        ((int*)ws)[0] = bf;
    }
}

// ---- init B ----------------------------------------------------------------
template <bool BF>
__device__ void initB_body(const void* xin, float* ws) {
    int tk = blockIdx.x;
    int t = tk >> 2, k = tk & 3;
    int b = threadIdx.x;
    bool z = false;
    size_t base = (size_t)b * TS * FF + (size_t)t * FF + k * GG;
#pragma unroll
    for (int g = 0; g < GG; ++g) {
        float v = ldv<BF>(xin, base + g);
        z |= !(v != v);
    }
    u64 m = __ballot(z);
    if (b == 0) {
        ((u64*)(ws + ZMASK_OFF))[tk] = m;
        ((int*)(ws + ZALL_OFF))[tk] = (m == ~0ull) ? 1 : 0;
    }
}
__global__ __launch_bounds__(64) void initB_kernel(const void* xin, float* ws) {
    int mode = ((const int*)ws)[0];
    if (mode) initB_body<true>(xin, ws);
    else      initB_body<false>(xin, ws);
}

// ---- weight prep (BF mode only): reorder into A-fragment layout ------------
__global__ __launch_bounds__(256) void prep_kernel(
    const void* Wm, const void* Zm, const void* Um, const void* Vm, float* ws) {
    if (((const int*)ws)[0] == 0) return;   // fp32 mode: no prep
    int gw = (int)((blockIdx.x * 256 + threadIdx.x) >> 6);   // matlayer*2560 + r
    int lane = threadIdx.x & 63;
    int ml = gw / 2560, r = gw - ml * 2560;
    int mi = ml >> 2, k = ml & 3;
    int RS = (mi == 2) ? (HH + GG) : HH;
    const void* M = (mi == 0) ? Wm : (mi == 1) ? Zm : (mi == 2) ? Um : Vm;
    const u16* src = (const u16*)M + (size_t)k * FIVE_H * RS + (size_t)r * RS + lane * 8;
    uint4 v = *(const uint4*)src;
    int q = lane >> 4, kb = (lane >> 2) & 3, qd = lane & 3;
    int slab = r >> 6, wv = (r >> 4) & 3, m = r & 15;
    u16* dst = (u16*)(ws + WFRAG_OFF) + (size_t)ml * (2560 * 512)
             + ((((size_t)(slab * 4 + q) * 4 + wv) * 4 + kb) * 64 + (qd * 16 + m)) * 8;
    *(uint4*)dst = v;
}

// ---- per-phase metadata ----------------------------------------------------
template <bool BF>
__device__ __forceinline__ void phase_meta(const void* bnd, const float* ws,
                                           int tau, int s,
                                           int& t, int& k, int& mcase, int& azf, int& nblk) {
    k = (tau & 1) + 2 * s;
    t = (tau - k) >> 1;
    mcase = 4; azf = 0; nblk = 0;
    if (t < 0 || t >= TS) { t = -1; return; }
    const float* sgsum = ws + SG_OFF;
    bool p_hi = (t == 0) ? (ldv<BF>(bnd, (size_t)k * TS) > 0.5f) : (sgsum[(t - 1) * 4 + k] > 16384.f);
    bool l_hi = (k == 0) ? (ldv<BF>(bnd, (size_t)t) > 0.5f) : (sgsum[t * 4 + (k - 1)] > 16384.f);
    mcase = p_hi ? (l_hi ? 3 : 2) : (l_hi ? 1 : 4);
    azf = ((const int*)(ws + ZALL_OFF))[t * 4 + k] ? 0 : 1;
    if (mcase == 4) return;
    int gs = (mcase == 1) ? 0 : 1, ng = 4 - gs;
    int nW = (t > 0) ? ng : 0;
    int nU = ((mcase == 1 || mcase == 3) && k > 0) ? ng : 0;
    int nV = azf ? nU : 0;
    nblk = (nW + nU + nV) * 32;
}

// ---- unit -> (matrix, gate) routing (fp32 path) ----------------------------
struct SlotInfo {
    const u16* M16; const float* Mf; int RS; int path; int g;
    const float* hv;
};
template <bool BF>
__device__ __forceinline__ SlotInfo slot_info(
    const void* Wm, const void* Zm, const void* Um, const void* Vm,
    const float* ws, int unit, int t, int k, int mcase) {
    int gs = (mcase == 1) ? 0 : 1, ng = 4 - gs;
    int nW = (t > 0) ? ng : 0;
    int nU = ((mcase == 1 || mcase == 3) && k > 0) ? ng : 0;
    int mat, g;
    if (unit < nW)            { mat = (mcase == 1) ? 0 : 1; g = gs + unit; }
    else if (unit < nW + nU)  { mat = 2; g = gs + unit - nW; }
    else                      { mat = 3; g = gs + unit - nW - nU; }
    const void* M = (mat == 0) ? Wm : (mat == 1) ? Zm : (mat == 2) ? Um : Vm;
    int kn = (k + 1 < LL) ? k + 1 : LL - 1;
    const float* ping = ws + PING_OFF;
    const float* prev = ping + (size_t)((t + 1) & 1) * LBH;   // [k][c][b]
    const float* cur  = ping + (size_t)(t & 1) * LBH;
    SlotInfo si;
    si.M16 = (const u16*)M; si.Mf = (const float*)M;
    si.RS = (mat == 2) ? (HH + GG) : HH;
    si.path = (mat <= 1) ? 0 : (mat == 2 ? 1 : 2);
    si.g = g;
    si.hv = (mat == 0) ? prev + (size_t)k * HH * BB
          : (mat == 1) ? prev + (size_t)kn * HH * BB
                       : cur + (size_t)(k - 1) * HH * BB;
    return si;
}

// ---- MFMA gemm slot (BF mode): LDS-free, sync-free, fragment-resident ------
__device__ void gemm_slot_bf(float* ws, int seg, int idx, int t, int k, int mcase) {
    int tid = threadIdx.x;
    int q = idx & 3, sub = (idx >> 2) & 7, unit = idx >> 5;
    int gs = (mcase == 1) ? 0 : 1, ng = 4 - gs;
    int nW = (t > 0) ? ng : 0;
    int nU = ((mcase == 1 || mcase == 3) && k > 0) ? ng : 0;
    int mat, g;
    if (unit < nW)            { mat = (mcase == 1) ? 0 : 1; g = gs + unit; }
    else if (unit < nW + nU)  { mat = 2; g = gs + unit - nW; }
    else                      { mat = 3; g = gs + unit - nW - nU; }
    int path = (mat <= 1) ? 0 : (mat == 2 ? 1 : 2);
    int slab = (g < 3) ? g * 8 + sub : 32 + sub;

    int lb, par;
    if (mat == 0)      { lb = k;  par = (t + 1) & 1; }
    else if (mat == 1) { lb = (k + 1 < LL) ? k + 1 : LL - 1; par = (t + 1) & 1; }
    else               { lb = k - 1; par = t & 1; }

    int lane = tid & 63, wave = tid >> 6;
    int m = lane & 15, qd = lane >> 4;

    const u16* af = (const u16*)(ws + WFRAG_OFF)
                  + (size_t)(mat * 4 + k) * (2560 * 512)
                  + (size_t)(slab * 4 + q) * 8192 + wave * 2048 + lane * 8;
    const u16* hf = (const u16*)(ws + HFRAG_OFF) + (size_t)((par * 4 + lb) * 2) * 32768;

    facc4 acc[4];
#pragma unroll
    for (int i = 0; i < 4; ++i) acc[i] = (facc4){0.f, 0.f, 0.f, 0.f};
#pragma unroll
    for (int kb = 0; kb < 4; ++kb) {
        bfrag8 a = *(const bfrag8*)(af + kb * 512);
        size_t hbk = (size_t)(q * 16 + kb * 4 + qd) * 512 + m * 8;
#pragma unroll
        for (int bg = 0; bg < 4; ++bg) {
            bfrag8 bh = *(const bfrag8*)(hf + hbk + bg * 128);
            bfrag8 bl = *(const bfrag8*)(hf + 32768 + hbk + bg * 128);
            acc[bg] = __builtin_amdgcn_mfma_f32_16x16x32_bf16(a, bh, acc[bg], 0, 0, 0);
            acc[bg] = __builtin_amdgcn_mfma_f32_16x16x32_bf16(a, bl, acc[bg], 0, 0, 0);
        }
    }
    float* pout = ws + PART_OFF + (size_t)seg * PART_SEG +
                  ((size_t)(path * 4 + q) * 4 + g) * (size_t)HH * BB;
#pragma unroll
    for (int bg = 0; bg < 4; ++bg)
#pragma unroll
        for (int reg = 0; reg < 4; ++reg)
            st_agent(&pout[(size_t)(sub * 64 + wave * 16 + qd * 4 + reg) * BB + bg * 16 + m],
                     acc[bg][reg]);
}

// ---- fp32 gemm slot (ACTIVE path, R4-proven math) --------------------------
__device__ void gemm_slot_f32(const void* Wm, const void* Zm, const void* Um, const void* Vm,
                              float* ws, float* wt, float* ht,
                              int seg, int idx, int t, int k, int mcase) {
    int tid = threadIdx.x;
    int q = idx & 3, sub = (idx >> 2) & 7, unit = idx >> 5;
    SlotInfo si = slot_info<false>(Wm, Zm, Um, Vm, ws, unit, t, k, mcase);
    int gbase = (si.g < 3) ? si.g * 512 : 2048;
    size_t mbase = (size_t)k * FIVE_H * si.RS + (size_t)(gbase + sub * 64) * si.RS + q * 128;

    int rg = tid >> 4, bg = tid & 15;
    float acc[4][4] = {{0.f}};
    for (int half = 0; half < 2; ++half) {
        int sr = tid >> 2, scg = (tid & 3) * 16;
        size_t rowoff = mbase + (size_t)sr * si.RS + half * 64 + scg;
#pragma unroll
        for (int i = 0; i < 4; ++i)
            *(float4*)&wt[sr * 68 + scg + 4 * i] = *(const float4*)(si.Mf + rowoff + 4 * i);
        int hc = tid >> 2, hb = (tid & 3) * 16;
        const float* hrow = si.hv + (size_t)(q * 128 + half * 64 + hc) * BB + hb;
#pragma unroll
        for (int i = 0; i < 4; ++i)
            *(float4*)&ht[hc * 68 + hb + 4 * i] = *(const float4*)(hrow + 4 * i);
        __syncthreads();
#pragma unroll 4
        for (int kk4 = 0; kk4 < 64; kk4 += 4) {
            float w[4][4], h[4][4];
#pragma unroll
            for (int j = 0; j < 4; ++j)
                *(float4*)w[j] = *(const float4*)&wt[(rg * 4 + j) * 68 + kk4];
#pragma unroll
            for (int j = 0; j < 4; ++j)
                *(float4*)h[j] = *(const float4*)&ht[(kk4 + j) * 68 + bg * 4];
#pragma unroll
            for (int rj = 0; rj < 4; ++rj)
#pragma unroll
                for (int bj = 0; bj < 4; ++bj)
#pragma unroll
                    for (int j = 0; j < 4; ++j)
                        acc[rj][bj] += w[rj][j] * h[j][bj];
        }
        __syncthreads();
    }
    float* pout = ws + PART_OFF + (size_t)seg * PART_SEG +
                  ((size_t)(si.path * 4 + q) * 4 + si.g) * (size_t)HH * BB;
#pragma unroll
    for (int rj = 0; rj < 4; ++rj)
#pragma unroll
        for (int c = 0; c < 4; ++c)
            st_agent(&pout[(size_t)(sub * 64 + rg * 4 + rj) * BB + bg * 4 + c], acc[rj][c]);
}

// ---- gates slot (agent-scope psum reads; rest unchanged) -------------------
template <bool BF>
__device__ void gates_slot(const void* xin, const void* Um, const void* Jm,
                           const void* bbias, float* ws, float* smem,
                           int seg, int jblk, int t, int k, int mcase, int azf) {
    float (*xs)[GG + 1] = (float (*)[GG + 1])smem;
    float* red = smem + BB * (GG + 1);
    int tid = threadIdx.x;
    int j = jblk * 4 + (tid >> 6);
    int b = tid & 63;

    {
        int b2 = tid >> 2, i0 = (tid & 3) * 4;
#pragma unroll
        for (int i = 0; i < 4; ++i) {
            float v = ldv<BF>(xin, (size_t)b2 * TS * FF + (size_t)t * FF + k * GG + i0 + i);
            xs[b2][i0 + i] = (v != v) ? 0.f : v;
        }
    }
    __syncthreads();
    u64 zm = ((const u64*)(ws + ZMASK_OFF))[t * 4 + k];
    bool zb = (zm >> b) & 1ull;

    float* cbuf = ws + C_OFF;
    const float* part = ws + PART_OFF + (size_t)seg * PART_SEG;
    float* cur = ws + PING_OFF + (size_t)(t & 1) * LBH;
    const float* prev = ws + PING_OFF + (size_t)((t + 1) & 1) * LBH;
    u16* hist = (u16*)(ws + HIST_OFF);
    size_t sidx = ((size_t)k * HH + j) * BB + b;

    float hn, sgv;
    if (mcase == 4) {
        float c = cbuf[sidx];
        float o = sigm(ldv<BF>(bbias, (size_t)k * FIVE_H + 1536 + j));
        hn = o * tanhf(c);
        float bsg = ldv<BF>(bbias, (size_t)k * FIVE_H + 2048 + j);
        sgv = fminf(fmaxf((bsg + 1.f) * 0.5f, 0.f), 1.f);
    } else {
        bool hasWZ = (t > 0);
        bool hasU = (k > 0) && (mcase != 2);
        const float* xv = &xs[b][0];
        auto psum = [&](int path, int g) -> float {
            float s = 0.f;
#pragma unroll
            for (int qq = 0; qq < 4; ++qq)
                s += ld_agent(&part[(((size_t)(path * 4 + qq) * 4 + g) * HH + j) * BB + b]);
            return s;
        };
        auto pre = [&](int g) -> float {
            int gb = (g < 3) ? g * 512 : 2048;
            float s = ldv<BF>(bbias, (size_t)k * FIVE_H + gb + j);
            if (hasWZ) s += psum(0, g);
            if (mcase == 2) {
                if (zb) {
                    const void* row = BF ? (const void*)((const u16*)Jm + (size_t)k * FIVE_H * GG + (size_t)(gb + j) * GG)
                                         : (const void*)((const float*)Jm + (size_t)k * FIVE_H * GG + (size_t)(gb + j) * GG);
                    s += dot16<BF>(row, xv);
                }
            } else {
                if (zb) {
                    if (hasU) s += psum(1, g);
                    const void* row = BF ? (const void*)((const u16*)Um + (size_t)k * FIVE_H * (HH + GG) + (size_t)(gb + j) * (HH + GG) + HH)
                                         : (const void*)((const float*)Um + (size_t)k * FIVE_H * (HH + GG) + (size_t)(gb + j) * (HH + GG) + HH);
                    s += dot16<BF>(row, xv);
                } else {
                    if (hasU && azf) s += psum(2, g);
                }
            }
            return s;
        };
        float preg = pre(1), prei = pre(2), presg = pre(3);
        float gg = tanhf(preg), ii = sigm(prei);
        float cnew;
        if (mcase == 1) {
            float f = sigm(pre(0));
            cnew = f * cbuf[sidx] + ii * gg;
        } else {
            cnew = ii * gg;
        }
        cbuf[sidx] = cnew;
        hn = (t > 0) ? prev[sidx] : 0.f;
        sgv = fminf(fmaxf((presg + 1.f) * 0.5f, 0.f), 1.f);
    }
    cur[sidx] = hn;
    u16 hi = f2bf_rne(hn);
    hist[((size_t)(t * 4 + k) * HH + j) * BB + b] = hi;
    if (BF) {
        u16 lo = f2bf_rne(hn - bf2f(hi));
        u16* hfw = (u16*)(ws + HFRAG_OFF) + (size_t)(((t & 1) * 4 + k) * 2) * 32768;
        size_t fo = ((size_t)(j >> 3) * 64 + b) * 8 + (j & 7);
        hfw[fo] = hi;
        hfw[32768 + fo] = lo;
    }

    float s = sgv;
#pragma unroll
    for (int off = 32; off > 0; off >>= 1) s += __shfl_down(s, off);
    if ((tid & 63) == 0) red[tid >> 6] = s;
    __syncthreads();
    if (tid == 0)
        atomicAdd(&ws[SG_OFF + t * 4 + k], red[0] + red[1] + red[2] + red[3]);
}

// ---- fused per-phase kernel ------------------------------------------------
__global__ __launch_bounds__(256, 2) void phase_kernel(
    const void* Wm, const void* Zm, const void* Um, const void* Vm,
    const void* xin, const void* Jm, const void* bbias,
    const void* bnd, float* ws, int tau) {
    __shared__ __align__(16) u16 gsm[26112];   // 52224 B: f32 staging / gates smem
    int mode = ((const int*)ws)[0];
    int t0, k0, m0, a0, n0, t1, k1, m1, a1, n1;
    if (mode) {
        phase_meta<true>(bnd, ws, tau, 0, t0, k0, m0, a0, n0);
        phase_meta<true>(bnd, ws, tau, 1, t1, k1, m1, a1, n1);
    } else {
        phase_meta<false>(bnd, ws, tau, 0, t0, k0, m0, a0, n0);
        phase_meta<false>(bnd, ws, tau, 1, t1, k1, m1, a1, n1);
    }
    int bid = blockIdx.x, tid = threadIdx.x;
    int* cnt = (int*)(ws + CNT_OFF) + tau * 32;
    int ntot = n0 + n1;

    // ---- gemm role ----
    if (bid < ntot) {
        if (mode) {
            if (bid < n0) gemm_slot_bf(ws, 0, bid, t0, k0, m0);
            else          gemm_slot_bf(ws, 1, bid - n0, t1, k1, m1);
        } else {
            float* fs = (float*)gsm;
            if (bid < n0) gemm_slot_f32(Wm, Zm, Um, Vm, ws, fs, fs + 4352, 0, bid, t0, k0, m0);
            else          gemm_slot_f32(Wm, Zm, Um, Vm, ws, fs, fs + 4352, 1, bid - n0, t1, k1, m1);
        }
        __syncthreads();            // drains each thread's vmcnt before arrive
        if (tid == 0) {
            int unit = bid >> 5;    // n0 is a multiple of 32 -> clean unit split
            if (atomicAdd(&cnt[2 + unit], 1) == 31)
                atomicAdd(&cnt[(bid < n0) ? 0 : 1], 1);
        }
    }

    // ---- gates role ----
    if (bid < 256) {
        int seg = bid >> 7, jblk = bid & 127;
        int t = seg ? t1 : t0, k = seg ? k1 : k0;
        int mc = seg ? m1 : m0, az = seg ? a1 : a0;
        int tgt = (seg ? n1 : n0) >> 5;
        if (t >= 0) {
            if (tid == 0) {
                while (__hip_atomic_load(&cnt[seg], __ATOMIC_RELAXED, __HIP_MEMORY_SCOPE_AGENT) < tgt)
                    __builtin_amdgcn_s_sleep(2);
            }
            __syncthreads();
            float* smem = (float*)gsm;
            if (mode) gates_slot<true>(xin, Um, Jm, bbias, ws, smem, seg, jblk, t, k, mc, az);
            else      gates_slot<false>(xin, Um, Jm, bbias, ws, smem, seg, jblk, t, k, mc, az);
        }
    }
}

// ---- excitation epilogue (unchanged) ---------------------------------------
template <bool BF>
__device__ void excite_body(const float* ws, float* smem, const void* Qm,
                            const void* Rm, const void* Wom, const void* bom,
                            void* out) {
    float (*sh_hcat)[LL * HH] = (float (*)[LL * HH])smem;
    float (*sh_r)[HH] = (float (*)[HH])(smem + TT * LL * HH);
    const u16* hhist = (const u16*)(ws + HIST_OFF);
    int tid = threadIdx.x;
    int b = blockIdx.x >> 5;
    int t0 = (blockIdx.x & 31) * TT;

    for (int idx = tid; idx < TT * LL * HH; idx += 256) {
        int tt = idx / (LL * HH);
        int f = idx % (LL * HH);
        int kk = f / HH, j = f % HH;
        sh_hcat[tt][f] = bf2f(hhist[((size_t)((t0 + tt) * 4 + kk) * HH + j) * BB + b]);
    }
    __syncthreads();

    int h0 = tid * 2;
    float acc0[TT] = {0, 0, 0, 0}, acc1[TT] = {0, 0, 0, 0};
    for (int kk = 0; kk < LL; ++kk) {
        float r0[TT] = {0, 0, 0, 0}, r1[TT] = {0, 0, 0, 0};
        if (BF) {
            const u32* qp = (const u32*)((const u16*)Qm + (size_t)kk * (LL * HH) * HH) + tid;
#pragma unroll 4
            for (int f = 0; f < LL * HH; ++f) {
                float2 qv = bf2x2(qp[(size_t)f * 256]);
#pragma unroll
                for (int tt = 0; tt < TT; ++tt) {
                    float hc = sh_hcat[tt][f];
                    r0[tt] += qv.x * hc;
                    r1[tt] += qv.y * hc;
                }
            }
        } else {
            const float2* qp = (const float2*)((const float*)Qm + (size_t)kk * (LL * HH) * HH) + tid;
#pragma unroll 4
            for (int f = 0; f < LL * HH; ++f) {
                float2 qv = qp[(size_t)f * 256];
#pragma unroll
                for (int tt = 0; tt < TT; ++tt) {
                    float hc = sh_hcat[tt][f];
                    r0[tt] += qv.x * hc;
                    r1[tt] += qv.y * hc;
                }
            }
        }
        __syncthreads();
#pragma unroll
        for (int tt = 0; tt < TT; ++tt) {
            sh_r[tt][h0]     = 1.f / (1.f + expf(-r0[tt]));
            sh_r[tt][h0 + 1] = 1.f / (1.f + expf(-r1[tt]));
        }
        __syncthreads();
        float m0[TT] = {0, 0, 0, 0}, m1v[TT] = {0, 0, 0, 0};
        if (BF) {
            const u32* rp = (const u32*)((const u16*)Rm + (size_t)kk * HH * HH) + tid;
#pragma unroll 4
            for (int hh2 = 0; hh2 < HH; ++hh2) {
                float2 rv = bf2x2(rp[(size_t)hh2 * 256]);
#pragma unroll
                for (int tt = 0; tt < TT; ++tt) {
                    float rr = sh_r[tt][hh2];
                    m0[tt] += rv.x * rr;
                    m1v[tt] += rv.y * rr;
                }
            }
        } else {
            const float2* rp = (const float2*)((const float*)Rm + (size_t)kk * HH * HH) + tid;
#pragma unroll 4
            for (int hh2 = 0; hh2 < HH; ++hh2) {
                float2 rv = rp[(size_t)hh2 * 256];
#pragma unroll
                for (int tt = 0; tt < TT; ++tt) {
                    float rr = sh_r[tt][hh2];
                    m0[tt] += rv.x * rr;
                    m1v[tt] += rv.y * rr;
                }
            }
        }
#pragma unroll
        for (int tt = 0; tt < TT; ++tt) {
            acc0[tt] += m0[tt] * sh_hcat[tt][kk * HH + h0];
            acc1[tt] += m1v[tt] * sh_hcat[tt][kk * HH + h0 + 1];
        }
    }
    __syncthreads();
#pragma unroll
    for (int tt = 0; tt < TT; ++tt) {
        sh_r[tt][h0]     = fmaxf(acc0[tt], 0.f);
        sh_r[tt][h0 + 1] = fmaxf(acc1[tt], 0.f);
    }
    __syncthreads();
    {
        int tt = tid >> 6, f = tid & 63;
        float acc = 0.f;
        if (BF) {
            const uint4* wp = (const uint4*)((const u16*)Wom + (size_t)f * HH);
            const float4* ev = (const float4*)sh_r[tt];
#pragma unroll 8
            for (int it = 0; it < HH / 8; ++it) {
                uint4 qv = wp[it];
                float4 e0 = ev[2 * it], e1 = ev[2 * it + 1];
                float2 a0 = bf2x2(qv.x), a1 = bf2x2(qv.y), a2 = bf2x2(qv.z), a3 = bf2x2(qv.w);
                acc += a0.x * e0.x + a0.y * e0.y + a1.x * e0.z + a1.y * e0.w +
                       a2.x * e1.x + a2.y * e1.y + a3.x * e1.z + a3.y * e1.w;
            }
        } else {
            const float4* wp = (const float4*)((const float*)Wom + (size_t)f * HH);
            const float4* ev = (const float4*)sh_r[tt];
#pragma unroll 8
            for (int it = 0; it < HH / 4; ++it) {
                float4 qv = wp[it], e = ev[it];
                acc += qv.x * e.x + qv.y * e.y + qv.z * e.z + qv.w * e.w;
            }
        }
        acc += ldv<BF>(bom, f);
        size_t oidx = ((size_t)b * TS + (t0 + tt)) * FF + f;
        if (BF) ((u16*)out)[oidx] = f2bf_rne(acc);
        else    ((float*)out)[oidx] = acc;
    }
}

__global__ __launch_bounds__(256) void excite_kernel(
    const float* ws, const void* Qm, const void* Rm, const void* Wom,
    const void* bom, void* out) {
    extern __shared__ float smem[];
    int mode = ((const int*)ws)[0];
    if (mode) excite_body<true>(ws, smem, Qm, Rm, Wom, bom, out);
    else      excite_body<false>(ws, smem, Qm, Rm, Wom, bom, out);
}

extern "C" void kernel_launch(void* const* d_in, const int* in_sizes, int n_in,
                              void* d_out, int out_size, void* d_ws, size_t ws_size,
                              hipStream_t stream) {
    const void* xin = d_in[0];
    const void* Wm  = d_in[1];
    const void* Zm  = d_in[2];
    const void* Um  = d_in[3];
    const void* Vm  = d_in[4];
    const void* Jm  = d_in[5];
    const void* bb  = d_in[6];
    const void* bnd = d_in[7];
    const void* Qm  = d_in[8];
    const void* Rm  = d_in[9];
    const void* Wo  = d_in[10];
    const void* bo  = d_in[11];
    float* ws = (float*)d_ws;

    initA_kernel<<<dim3(512), dim3(256), 0, stream>>>((const u16*)bnd, ws);
    initB_kernel<<<dim3(512), dim3(64), 0, stream>>>(xin, ws);
    prep_kernel<<<dim3(10240), dim3(256), 0, stream>>>(Wm, Zm, Um, Vm, ws);
    for (int tau = 0; tau < 2 * TS + LL - 2; ++tau) {   // 258 fused phases
        phase_kernel<<<dim3(768), dim3(256), 0, stream>>>(
            Wm, Zm, Um, Vm, xin, Jm, bb, bnd, ws, tau);
    }
    size_t exc_smem = (TT * LL * HH + TT * HH) * sizeof(float);  // 40 KB
    excite_kernel<<<dim3(2048), dim3(256), exc_smem, stream>>>(
        ws, Qm, Rm, Wo, bo, d_out);
}

// Round 4
// 5671.269 us; speedup vs baseline: 1.5347x; 1.5347x over previous
//
#include <hip/hip_runtime.h>
#include <hip/hip_bf16.h>

// ---------------------------------------------------------------------------
// StandardMRALSTM — round 9: R2 scan (reverted, proven 6675us) + MFMA excite.
//  * R3 measured: excite_kernel = 3047us (46% of total), MfmaUtil=0, VALU 54%
//    -> fp32 scalar GEMM chain on the vector ALU. Replaced with split-bf16
//    MFMA pipeline (validated split technique, absmax-neutral):
//      fragprep(Q,R) -> transpose(hist->hist_T) -> per k: E1 (r = sigmoid
//      (h_cat @ Q), K=2048) ; E2 (mul1 = r @ R, x h, accumulate excited) ;
//      then E3 (relu + @Wo^T + bo).
//  * Scratch overlaid on scan-dead regions (PART / HIST / WFRAG spare):
//    workspace high-water IDENTICAL to the passing R2 layout (90.7 MB).
//  * R3 fusion (spin-wait) regressed scan by 2ms -> reverted to 2 dispatches.
// ---------------------------------------------------------------------------

#define LL 4
#define HH 512
#define TS 128
#define GG 16
#define BB 64
#define FF 64
#define FIVE_H 2560
#define LBH (LL * BB * HH)

typedef unsigned short u16;
typedef unsigned int u32;
typedef unsigned long long u64;

typedef short bfrag8 __attribute__((ext_vector_type(8)));   // 8 bf16
typedef float facc4 __attribute__((ext_vector_type(4)));    // 4 fp32

#define SG_OFF    64
#define ZALL_OFF  1024
#define ZMASK_OFF 2048
#define C_OFF     4096
#define PING_OFF  (C_OFF + LBH)                       // 135168
#define PART_OFF  (PING_OFF + 2 * LBH)                // 397312
#define PART_SEG  (12 * 4 * HH * BB)                  // 1572864 floats per seg
#define HIST_OFF  (PART_OFF + 2 * PART_SEG)           // 3543040 (u16 region, 16.7M u16)
#define HFRAG_OFF (HIST_OFF + 8388608)                // 11931648 (u16 region)
#define WFRAG_OFF (HFRAG_OFF + 262144)                // 12193792 (u16 region, 20.97M u16)
// ---- excite-phase overlays (all scan-dead at excite time) ------------------
// hist_T  : u16[64b][128t][2048f]      at WFRAG_OFF       (16777216 u16)
// Qfrag hi: u16[4k][256fb][512h][8]    at WFRAG_OFF+16777216 u16 (4194304 u16)
// Qfrag lo: u16 same                   at PART_OFF        (4194304 u16)
// Rfrag hi: u16[4k][64hb][512g][8]     at PART_OFF+4194304 u16   (1048576 u16)
// Rfrag lo: u16 same                   at +1048576 u16    (ends exactly at HIST_OFF)
// r hi    : u16[64b][128t][512h]       at HIST_OFF        (4194304 u16)
// r lo    : u16 same                   at +4194304 u16
// excited : f32[8192bt][512g]          at HIST_OFF+4194304 floats (ends at HFRAG_OFF)
#define EXC_OFF   (HIST_OFF + 4194304)                // 7737344 floats

__device__ __forceinline__ float bf2f(u16 u) { return __uint_as_float(((u32)u) << 16); }
__device__ __forceinline__ float2 bf2x2(u32 u) {
    float2 r;
    r.x = __uint_as_float(u << 16);
    r.y = __uint_as_float(u & 0xFFFF0000u);
    return r;
}
__device__ __forceinline__ u16 f2bf_rne(float f) {
    u32 x = __float_as_uint(f);
    return (u16)((x + 0x7FFFu + ((x >> 16) & 1u)) >> 16);
}
__device__ __forceinline__ float sigm(float x) { return 1.f / (1.f + expf(-x)); }

template <bool BF>
__device__ __forceinline__ float ldv(const void* p, size_t i) {
    return BF ? bf2f(((const u16*)p)[i]) : ((const float*)p)[i];
}

template <bool BF>
__device__ __forceinline__ float dot16(const void* row, const float* xs) {
    float s = 0.f;
    if (BF) {
        const uint4* p = (const uint4*)row;
        uint4 a = p[0], b4 = p[1];
        float2 v;
        v = bf2x2(a.x);  s += v.x * xs[0]  + v.y * xs[1];
        v = bf2x2(a.y);  s += v.x * xs[2]  + v.y * xs[3];
        v = bf2x2(a.z);  s += v.x * xs[4]  + v.y * xs[5];
        v = bf2x2(a.w);  s += v.x * xs[6]  + v.y * xs[7];
        v = bf2x2(b4.x); s += v.x * xs[8]  + v.y * xs[9];
        v = bf2x2(b4.y); s += v.x * xs[10] + v.y * xs[11];
        v = bf2x2(b4.z); s += v.x * xs[12] + v.y * xs[13];
        v = bf2x2(b4.w); s += v.x * xs[14] + v.y * xs[15];
    } else {
        const float4* p = (const float4*)row;
#pragma unroll
        for (int i = 0; i < 4; ++i) {
            float4 v = p[i];
            s += v.x * xs[4 * i] + v.y * xs[4 * i + 1] + v.z * xs[4 * i + 2] + v.w * xs[4 * i + 3];
        }
    }
    return s;
}

// ---- init A ----------------------------------------------------------------
__global__ void initA_kernel(const u16* __restrict__ bnd_raw, float* __restrict__ ws) {
    size_t i = (size_t)blockIdx.x * 256 + threadIdx.x;
    if (i < LBH) ws[C_OFF + i] = 0.f;
    if (i < 512) ws[SG_OFF + i] = 0.f;
    if (i == 0) {
        int bf = 1;
        for (int j = 0; j < 32; ++j) {
            float v = bf2f(bnd_raw[2 * j]);
            if (!(v >= 0.f && v <= 1.f)) bf = 0;
        }
        ((int*)ws)[0] = bf;
    }
}

// ---- init B ----------------------------------------------------------------
template <bool BF>
__device__ void initB_body(const void* xin, float* ws) {
    int tk = blockIdx.x;
    int t = tk >> 2, k = tk & 3;
    int b = threadIdx.x;
    bool z = false;
    size_t base = (size_t)b * TS * FF + (size_t)t * FF + k * GG;
#pragma unroll
    for (int g = 0; g < GG; ++g) {
        float v = ldv<BF>(xin, base + g);
        z |= !(v != v);
    }
    u64 m = __ballot(z);
    if (b == 0) {
        ((u64*)(ws + ZMASK_OFF))[tk] = m;
        ((int*)(ws + ZALL_OFF))[tk] = (m == ~0ull) ? 1 : 0;
    }
}
__global__ __launch_bounds__(64) void initB_kernel(const void* xin, float* ws) {
    int mode = ((const int*)ws)[0];
    if (mode) initB_body<true>(xin, ws);
    else      initB_body<false>(xin, ws);
}

// ---- weight prep (BF mode only): reorder into A-fragment layout ------------
__global__ __launch_bounds__(256) void prep_kernel(
    const void* Wm, const void* Zm, const void* Um, const void* Vm, float* ws) {
    if (((const int*)ws)[0] == 0) return;   // fp32 mode: no prep
    int gw = (int)((blockIdx.x * 256 + threadIdx.x) >> 6);   // matlayer*2560 + r
    int lane = threadIdx.x & 63;
    int ml = gw / 2560, r = gw - ml * 2560;
    int mi = ml >> 2, k = ml & 3;
    int RS = (mi == 2) ? (HH + GG) : HH;
    const void* M = (mi == 0) ? Wm : (mi == 1) ? Zm : (mi == 2) ? Um : Vm;
    const u16* src = (const u16*)M + (size_t)k * FIVE_H * RS + (size_t)r * RS + lane * 8;
    uint4 v = *(const uint4*)src;
    int q = lane >> 4, kb = (lane >> 2) & 3, qd = lane & 3;
    int slab = r >> 6, wv = (r >> 4) & 3, m = r & 15;
    u16* dst = (u16*)(ws + WFRAG_OFF) + (size_t)ml * (2560 * 512)
             + ((((size_t)(slab * 4 + q) * 4 + wv) * 4 + kb) * 64 + (qd * 16 + m)) * 8;
    *(uint4*)dst = v;
}

// ---- per-phase metadata ----------------------------------------------------
template <bool BF>
__device__ __forceinline__ void phase_meta(const void* bnd, const float* ws,
                                           int tau, int s,
                                           int& t, int& k, int& mcase, int& azf, int& nblk) {
    k = (tau & 1) + 2 * s;
    t = (tau - k) >> 1;
    mcase = 4; azf = 0; nblk = 0;
    if (t < 0 || t >= TS) { t = -1; return; }
    const float* sgsum = ws + SG_OFF;
    bool p_hi = (t == 0) ? (ldv<BF>(bnd, (size_t)k * TS) > 0.5f) : (sgsum[(t - 1) * 4 + k] > 16384.f);
    bool l_hi = (k == 0) ? (ldv<BF>(bnd, (size_t)t) > 0.5f) : (sgsum[t * 4 + (k - 1)] > 16384.f);
    mcase = p_hi ? (l_hi ? 3 : 2) : (l_hi ? 1 : 4);
    azf = ((const int*)(ws + ZALL_OFF))[t * 4 + k] ? 0 : 1;
    if (mcase == 4) return;
    int gs = (mcase == 1) ? 0 : 1, ng = 4 - gs;
    int nW = (t > 0) ? ng : 0;
    int nU = ((mcase == 1 || mcase == 3) && k > 0) ? ng : 0;
    int nV = azf ? nU : 0;
    nblk = (nW + nU + nV) * 32;
}

// ---- unit -> (matrix, gate) routing ----------------------------------------
struct SlotInfo {
    const u16* M16; const float* Mf; int RS; int path; int g;
    const float* hv;
};
template <bool BF>
__device__ __forceinline__ SlotInfo slot_info(
    const void* Wm, const void* Zm, const void* Um, const void* Vm,
    const float* ws, int unit, int t, int k, int mcase) {
    int gs = (mcase == 1) ? 0 : 1, ng = 4 - gs;
    int nW = (t > 0) ? ng : 0;
    int nU = ((mcase == 1 || mcase == 3) && k > 0) ? ng : 0;
    int mat, g;
    if (unit < nW)            { mat = (mcase == 1) ? 0 : 1; g = gs + unit; }
    else if (unit < nW + nU)  { mat = 2; g = gs + unit - nW; }
    else                      { mat = 3; g = gs + unit - nW - nU; }
    const void* M = (mat == 0) ? Wm : (mat == 1) ? Zm : (mat == 2) ? Um : Vm;
    int kn = (k + 1 < LL) ? k + 1 : LL - 1;
    const float* ping = ws + PING_OFF;
    const float* prev = ping + (size_t)((t + 1) & 1) * LBH;   // [k][c][b]
    const float* cur  = ping + (size_t)(t & 1) * LBH;
    SlotInfo si;
    si.M16 = (const u16*)M; si.Mf = (const float*)M;
    si.RS = (mat == 2) ? (HH + GG) : HH;
    si.path = (mat <= 1) ? 0 : (mat == 2 ? 1 : 2);
    si.g = g;
    si.hv = (mat == 0) ? prev + (size_t)k * HH * BB
          : (mat == 1) ? prev + (size_t)kn * HH * BB
                       : cur + (size_t)(k - 1) * HH * BB;
    return si;
}

// ---- MFMA gemm slot (BF mode): LDS-free, fragment-resident -----------------
__device__ void gemm_slot_bf(float* ws, int seg, int idx, int t, int k, int mcase) {
    int tid = threadIdx.x;
    int q = idx & 3, sub = (idx >> 2) & 7, unit = idx >> 5;
    int gs = (mcase == 1) ? 0 : 1, ng = 4 - gs;
    int nW = (t > 0) ? ng : 0;
    int nU = ((mcase == 1 || mcase == 3) && k > 0) ? ng : 0;
    int mat, g;
    if (unit < nW)            { mat = (mcase == 1) ? 0 : 1; g = gs + unit; }
    else if (unit < nW + nU)  { mat = 2; g = gs + unit - nW; }
    else                      { mat = 3; g = gs + unit - nW - nU; }
    int path = (mat <= 1) ? 0 : (mat == 2 ? 1 : 2);
    int slab = (g < 3) ? g * 8 + sub : 32 + sub;

    int lb, par;
    if (mat == 0)      { lb = k;  par = (t + 1) & 1; }
    else if (mat == 1) { lb = (k + 1 < LL) ? k + 1 : LL - 1; par = (t + 1) & 1; }
    else               { lb = k - 1; par = t & 1; }

    int lane = tid & 63, wave = tid >> 6;
    int m = lane & 15, qd = lane >> 4;

    const u16* af = (const u16*)(ws + WFRAG_OFF)
                  + (size_t)(mat * 4 + k) * (2560 * 512)
                  + (size_t)(slab * 4 + q) * 8192 + wave * 2048 + lane * 8;
    const u16* hf = (const u16*)(ws + HFRAG_OFF) + (size_t)((par * 4 + lb) * 2) * 32768;

    facc4 acc[4];
#pragma unroll
    for (int i = 0; i < 4; ++i) acc[i] = (facc4){0.f, 0.f, 0.f, 0.f};
#pragma unroll
    for (int kb = 0; kb < 4; ++kb) {
        bfrag8 a = *(const bfrag8*)(af + kb * 512);
        size_t hbk = (size_t)(q * 16 + kb * 4 + qd) * 512 + m * 8;
#pragma unroll
        for (int bg = 0; bg < 4; ++bg) {
            bfrag8 bh = *(const bfrag8*)(hf + hbk + bg * 128);
            bfrag8 bl = *(const bfrag8*)(hf + 32768 + hbk + bg * 128);
            acc[bg] = __builtin_amdgcn_mfma_f32_16x16x32_bf16(a, bh, acc[bg], 0, 0, 0);
            acc[bg] = __builtin_amdgcn_mfma_f32_16x16x32_bf16(a, bl, acc[bg], 0, 0, 0);
        }
    }
    float* pout = ws + PART_OFF + (size_t)seg * PART_SEG +
                  ((size_t)(path * 4 + q) * 4 + g) * (size_t)HH * BB;
#pragma unroll
    for (int bg = 0; bg < 4; ++bg)
#pragma unroll
        for (int reg = 0; reg < 4; ++reg)
            pout[(size_t)(sub * 64 + wave * 16 + qd * 4 + reg) * BB + bg * 16 + m] = acc[bg][reg];
}

// ---- fp32 gemm slot (ACTIVE path, R4-proven) -------------------------------
__device__ void gemm_slot_f32(const void* Wm, const void* Zm, const void* Um, const void* Vm,
                              float* ws, float* wt, float* ht,
                              int seg, int idx, int t, int k, int mcase) {
    int tid = threadIdx.x;
    int q = idx & 3, sub = (idx >> 2) & 7, unit = idx >> 5;
    SlotInfo si = slot_info<false>(Wm, Zm, Um, Vm, ws, unit, t, k, mcase);
    int gbase = (si.g < 3) ? si.g * 512 : 2048;
    size_t mbase = (size_t)k * FIVE_H * si.RS + (size_t)(gbase + sub * 64) * si.RS + q * 128;

    int rg = tid >> 4, bg = tid & 15;
    float acc[4][4] = {{0.f}};
    for (int half = 0; half < 2; ++half) {
        int sr = tid >> 2, scg = (tid & 3) * 16;
        size_t rowoff = mbase + (size_t)sr * si.RS + half * 64 + scg;
#pragma unroll
        for (int i = 0; i < 4; ++i)
            *(float4*)&wt[sr * 68 + scg + 4 * i] = *(const float4*)(si.Mf + rowoff + 4 * i);
        int hc = tid >> 2, hb = (tid & 3) * 16;
        const float* hrow = si.hv + (size_t)(q * 128 + half * 64 + hc) * BB + hb;
#pragma unroll
        for (int i = 0; i < 4; ++i)
            *(float4*)&ht[hc * 68 + hb + 4 * i] = *(const float4*)(hrow + 4 * i);
        __syncthreads();
#pragma unroll 4
        for (int kk4 = 0; kk4 < 64; kk4 += 4) {
            float w[4][4], h[4][4];
#pragma unroll
            for (int j = 0; j < 4; ++j)
                *(float4*)w[j] = *(const float4*)&wt[(rg * 4 + j) * 68 + kk4];
#pragma unroll
            for (int j = 0; j < 4; ++j)
                *(float4*)h[j] = *(const float4*)&ht[(kk4 + j) * 68 + bg * 4];
#pragma unroll
            for (int rj = 0; rj < 4; ++rj)
#pragma unroll
                for (int bj = 0; bj < 4; ++bj)
#pragma unroll
                    for (int j = 0; j < 4; ++j)
                        acc[rj][bj] += w[rj][j] * h[j][bj];
        }
        __syncthreads();
    }
    float* pout = ws + PART_OFF + (size_t)seg * PART_SEG +
                  ((size_t)(si.path * 4 + q) * 4 + si.g) * (size_t)HH * BB;
#pragma unroll
    for (int rj = 0; rj < 4; ++rj) {
        float4 vv = make_float4(acc[rj][0], acc[rj][1], acc[rj][2], acc[rj][3]);
        *(float4*)&pout[(size_t)(sub * 64 + rg * 4 + rj) * BB + bg * 4] = vv;
    }
}

__global__ __launch_bounds__(256) void gemm_phase_kernel(
    const void* Wm, const void* Zm, const void* Um, const void* Vm,
    const void* bnd, float* ws, int tau) {
    __shared__ __align__(16) u16 gsm[26112];
    int mode = ((const int*)ws)[0];
    if (mode) {
        int t0, k0, m0, a0, n0, t1, k1, m1, a1, n1;
        phase_meta<true>(bnd, ws, tau, 0, t0, k0, m0, a0, n0);
        phase_meta<true>(bnd, ws, tau, 1, t1, k1, m1, a1, n1);
        int bid = blockIdx.x;
        if (bid < n0)           gemm_slot_bf(ws, 0, bid, t0, k0, m0);
        else if (bid < n0 + n1) gemm_slot_bf(ws, 1, bid - n0, t1, k1, m1);
    } else {
        float* fs = (float*)gsm;
        int t0, k0, m0, a0, n0, t1, k1, m1, a1, n1;
        phase_meta<false>(bnd, ws, tau, 0, t0, k0, m0, a0, n0);
        phase_meta<false>(bnd, ws, tau, 1, t1, k1, m1, a1, n1);
        int bid = blockIdx.x;
        if (bid < n0)           gemm_slot_f32(Wm, Zm, Um, Vm, ws, fs, fs + 4352, 0, bid, t0, k0, m0);
        else if (bid < n0 + n1) gemm_slot_f32(Wm, Zm, Um, Vm, ws, fs, fs + 4352, 1, bid - n0, t1, k1, m1);
    }
}

// ---- gates slot (R2-proven) ------------------------------------------------
template <bool BF>
__device__ void gates_slot(const void* xin, const void* Um, const void* Jm,
                           const void* bbias, float* ws, float* smem,
                           int seg, int jblk, int t, int k, int mcase, int azf) {
    float (*xs)[GG + 1] = (float (*)[GG + 1])smem;
    float* red = smem + BB * (GG + 1);
    int tid = threadIdx.x;
    int j = jblk * 4 + (tid >> 6);
    int b = tid & 63;

    {
        int b2 = tid >> 2, i0 = (tid & 3) * 4;
#pragma unroll
        for (int i = 0; i < 4; ++i) {
            float v = ldv<BF>(xin, (size_t)b2 * TS * FF + (size_t)t * FF + k * GG + i0 + i);
            xs[b2][i0 + i] = (v != v) ? 0.f : v;
        }
    }
    __syncthreads();
    u64 zm = ((const u64*)(ws + ZMASK_OFF))[t * 4 + k];
    bool zb = (zm >> b) & 1ull;

    float* cbuf = ws + C_OFF;
    const float* part = ws + PART_OFF + (size_t)seg * PART_SEG;
    float* cur = ws + PING_OFF + (size_t)(t & 1) * LBH;
    const float* prev = ws + PING_OFF + (size_t)((t + 1) & 1) * LBH;
    u16* hist = (u16*)(ws + HIST_OFF);
    size_t sidx = ((size_t)k * HH + j) * BB + b;

    float hn, sgv;
    if (mcase == 4) {
        float c = cbuf[sidx];
        float o = sigm(ldv<BF>(bbias, (size_t)k * FIVE_H + 1536 + j));
        hn = o * tanhf(c);
        float bsg = ldv<BF>(bbias, (size_t)k * FIVE_H + 2048 + j);
        sgv = fminf(fmaxf((bsg + 1.f) * 0.5f, 0.f), 1.f);
    } else {
        bool hasWZ = (t > 0);
        bool hasU = (k > 0) && (mcase != 2);
        const float* xv = &xs[b][0];
        auto psum = [&](int path, int g) -> float {
            float s = 0.f;
#pragma unroll
            for (int qq = 0; qq < 4; ++qq)
                s += part[(((size_t)(path * 4 + qq) * 4 + g) * HH + j) * BB + b];
            return s;
        };
        auto pre = [&](int g) -> float {
            int gb = (g < 3) ? g * 512 : 2048;
            float s = ldv<BF>(bbias, (size_t)k * FIVE_H + gb + j);
            if (hasWZ) s += psum(0, g);
            if (mcase == 2) {
                if (zb) {
                    const void* row = BF ? (const void*)((const u16*)Jm + (size_t)k * FIVE_H * GG + (size_t)(gb + j) * GG)
                                         : (const void*)((const float*)Jm + (size_t)k * FIVE_H * GG + (size_t)(gb + j) * GG);
                    s += dot16<BF>(row, xv);
                }
            } else {
                if (zb) {
                    if (hasU) s += psum(1, g);
                    const void* row = BF ? (const void*)((const u16*)Um + (size_t)k * FIVE_H * (HH + GG) + (size_t)(gb + j) * (HH + GG) + HH)
                                         : (const void*)((const float*)Um + (size_t)k * FIVE_H * (HH + GG) + (size_t)(gb + j) * (HH + GG) + HH);
                    s += dot16<BF>(row, xv);
                } else {
                    if (hasU && azf) s += psum(2, g);
                }
            }
            return s;
        };
        float preg = pre(1), prei = pre(2), presg = pre(3);
        float gg = tanhf(preg), ii = sigm(prei);
        float cnew;
        if (mcase == 1) {
            float f = sigm(pre(0));
            cnew = f * cbuf[sidx] + ii * gg;
        } else {
            cnew = ii * gg;
        }
        cbuf[sidx] = cnew;
        hn = (t > 0) ? prev[sidx] : 0.f;
        sgv = fminf(fmaxf((presg + 1.f) * 0.5f, 0.f), 1.f);
    }
    cur[sidx] = hn;
    u16 hi = f2bf_rne(hn);
    hist[((size_t)(t * 4 + k) * HH + j) * BB + b] = hi;
    if (BF) {
        u16 lo = f2bf_rne(hn - bf2f(hi));
        u16* hfw = (u16*)(ws + HFRAG_OFF) + (size_t)(((t & 1) * 4 + k) * 2) * 32768;
        size_t fo = ((size_t)(j >> 3) * 64 + b) * 8 + (j & 7);
        hfw[fo] = hi;
        hfw[32768 + fo] = lo;
    }

    float s = sgv;
#pragma unroll
    for (int off = 32; off > 0; off >>= 1) s += __shfl_down(s, off);
    if ((tid & 63) == 0) red[tid >> 6] = s;
    __syncthreads();
    if (tid == 0)
        atomicAdd(&ws[SG_OFF + t * 4 + k], red[0] + red[1] + red[2] + red[3]);
}

template <bool BF>
__device__ void gates_phase_body(const void* xin, const void* Um, const void* Jm,
                                 const void* bbias, const void* bnd, float* ws,
                                 float* smem, int tau) {
    int seg = blockIdx.x >> 7, jblk = blockIdx.x & 127;
    int t, k, mc, az, nb;
    phase_meta<BF>(bnd, ws, tau, seg, t, k, mc, az, nb);
    if (t >= 0)
        gates_slot<BF>(xin, Um, Jm, bbias, ws, smem, seg, jblk, t, k, mc, az);
}
__global__ __launch_bounds__(256) void gates_phase_kernel(
    const void* xin, const void* Um, const void* Jm, const void* bbias,
    const void* bnd, float* ws, int tau) {
    __shared__ float smem[BB * (GG + 1) + 4];
    int mode = ((const int*)ws)[0];
    if (mode) gates_phase_body<true>(xin, Um, Jm, bbias, bnd, ws, smem, tau);
    else      gates_phase_body<false>(xin, Um, Jm, bbias, bnd, ws, smem, tau);
}

// ---- excite stage 0: fragment prep for Q (which=0) / R (which=1) -----------
// dst B-frag layout: [(ko*(Fext/8) + fb)*512 + n]*8 + (f&7), hi & lo parts.
template <bool BF>
__device__ void fragprep_body(const void* src, float* ws, int Fext, int which) {
    int tid = threadIdx.x;
    int nfg = Fext >> 6;
    int ko = blockIdx.x / nfg, fg = blockIdx.x % nfg;
    size_t kstride = (size_t)Fext * 512;
    u16 *dhi, *dlo;
    if (which == 0) { dhi = (u16*)(ws + WFRAG_OFF) + 16777216; dlo = (u16*)(ws + PART_OFF); }
    else            { dhi = (u16*)(ws + PART_OFF) + 4194304;   dlo = dhi + 1048576; }
    __shared__ float S[64][129];
    for (int gc = 0; gc < 4; ++gc) {
        for (int it = 0; it < 32; ++it) {
            int idx = it * 256 + tid;
            int f = idx >> 7, n = idx & 127;
            S[f][n] = ldv<BF>(src, ko * kstride + (size_t)(fg * 64 + f) * 512 + gc * 128 + n);
        }
        __syncthreads();
        for (int it = 0; it < 4; ++it) {
            int idx = it * 256 + tid;
            int fbl = idx >> 7, n = idx & 127;
            u32 hiw[4], low[4];
#pragma unroll
            for (int jp = 0; jp < 4; ++jp) {
                float v0 = S[fbl * 8 + 2 * jp][n], v1 = S[fbl * 8 + 2 * jp + 1][n];
                u16 h0 = f2bf_rne(v0), h1 = f2bf_rne(v1);
                u16 l0 = f2bf_rne(v0 - bf2f(h0)), l1 = f2bf_rne(v1 - bf2f(h1));
                hiw[jp] = (u32)h0 | ((u32)h1 << 16);
                low[jp] = (u32)l0 | ((u32)l1 << 16);
            }
            size_t o = (((size_t)ko * (Fext >> 3) + fg * 8 + fbl) * 512 + gc * 128 + n) * 8;
            *(uint4*)(dhi + o) = make_uint4(hiw[0], hiw[1], hiw[2], hiw[3]);
            *(uint4*)(dlo + o) = make_uint4(low[0], low[1], low[2], low[3]);
        }
        __syncthreads();
    }
}
__global__ __launch_bounds__(256) void fragprep_kernel(const void* src, float* ws,
                                                       int Fext, int which) {
    int mode = ((const int*)ws)[0];
    if (mode) fragprep_body<true>(src, ws, Fext, which);
    else      fragprep_body<false>(src, ws, Fext, which);
}

// ---- excite stage 1: hist [tk][j][b] -> hist_T [b][t][f=k*512+j] -----------
__global__ __launch_bounds__(256) void transpose_kernel(float* ws) {
    int tk = blockIdx.x;
    int t = tk >> 2, k = tk & 3;
    const u16* hist = (const u16*)(ws + HIST_OFF);
    u16* hT = (u16*)(ws + WFRAG_OFF);
    int tid = threadIdx.x;
    for (int it = 0; it < 16; ++it) {        // 64 b * 64 j-octs
        int idx = it * 256 + tid;
        int b = idx >> 6, jo = idx & 63;
        u16 tmp[8];
#pragma unroll
        for (int j = 0; j < 8; ++j)
            tmp[j] = hist[((size_t)tk * 512 + jo * 8 + j) * 64 + b];
        *(uint4*)&hT[((size_t)(b * 128 + t)) * 2048 + k * 512 + jo * 8] = *(uint4*)tmp;
    }
}

// ---- excite stage 2 (per k): r = sigmoid(h_cat @ Q[k]), split hi/lo --------
__global__ __launch_bounds__(256) void exciteR_kernel(float* ws, int k) {
    int tid = threadIdx.x, lane = tid & 63, w = tid >> 6;
    int m = lane & 15, qd = lane >> 4;
    int bb = blockIdx.x >> 2, nt4 = blockIdx.x & 3;
    int h0 = nt4 * 128;
    const u16* hT = (const u16*)(ws + WFRAG_OFF);
    const u16* qhi = hT + 16777216;
    const u16* qlo = (const u16*)(ws + PART_OFF);
    const u16* A = hT + (size_t)(bb * 128 + w * 32) * 2048;

    facc4 acc[2][8];
#pragma unroll
    for (int i = 0; i < 2; ++i)
#pragma unroll
        for (int j = 0; j < 8; ++j) acc[i][j] = (facc4){0.f, 0.f, 0.f, 0.f};

    for (int kc = 0; kc < 64; ++kc) {
        bfrag8 a0 = *(const bfrag8*)(A + (size_t)m * 2048 + kc * 32 + qd * 8);
        bfrag8 a1 = *(const bfrag8*)(A + (size_t)(16 + m) * 2048 + kc * 32 + qd * 8);
        size_t qb = ((size_t)(k * 256 + kc * 4 + qd) * 512 + h0 + m) * 8;
#pragma unroll
        for (int nt = 0; nt < 8; ++nt) {
            bfrag8 bh = *(const bfrag8*)(qhi + qb + nt * 128);
            bfrag8 bl = *(const bfrag8*)(qlo + qb + nt * 128);
            acc[0][nt] = __builtin_amdgcn_mfma_f32_16x16x32_bf16(a0, bh, acc[0][nt], 0, 0, 0);
            acc[0][nt] = __builtin_amdgcn_mfma_f32_16x16x32_bf16(a0, bl, acc[0][nt], 0, 0, 0);
            acc[1][nt] = __builtin_amdgcn_mfma_f32_16x16x32_bf16(a1, bh, acc[1][nt], 0, 0, 0);
            acc[1][nt] = __builtin_amdgcn_mfma_f32_16x16x32_bf16(a1, bl, acc[1][nt], 0, 0, 0);
        }
    }
    u16* rhi = (u16*)(ws + HIST_OFF);
    u16* rlo = rhi + 4194304;
#pragma unroll
    for (int mt = 0; mt < 2; ++mt)
#pragma unroll
        for (int nt = 0; nt < 8; ++nt)
#pragma unroll
            for (int reg = 0; reg < 4; ++reg) {
                float rv = sigm(acc[mt][nt][reg]);
                int t = w * 32 + mt * 16 + qd * 4 + reg;
                int h = h0 + nt * 16 + m;
                size_t o = (size_t)(bb * 128 + t) * 512 + h;
                u16 hi = f2bf_rne(rv);
                rhi[o] = hi;
                rlo[o] = f2bf_rne(rv - bf2f(hi));
            }
}

// ---- excite stage 3 (per k): mul1 = r @ R[k]; excited += mul1 * h ----------
__global__ __launch_bounds__(256) void exciteM_kernel(float* ws, int k) {
    int tid = threadIdx.x, lane = tid & 63, w = tid >> 6;
    int m = lane & 15, qd = lane >> 4;
    int bb = blockIdx.x >> 2, tt = blockIdx.x & 3;
    int g0 = w * 128;
    const u16* rhi = (const u16*)(ws + HIST_OFF);
    const u16* rlo = rhi + 4194304;
    const u16* rfhi = (const u16*)(ws + PART_OFF) + 4194304;
    const u16* rflo = rfhi + 1048576;
    const u16* Ahi = rhi + (size_t)(bb * 128 + tt * 32) * 512;
    const u16* Alo = rlo + (size_t)(bb * 128 + tt * 32) * 512;

    facc4 acc[2][8];
#pragma unroll
    for (int i = 0; i < 2; ++i)
#pragma unroll
        for (int j = 0; j < 8; ++j) acc[i][j] = (facc4){0.f, 0.f, 0.f, 0.f};

    for (int kc = 0; kc < 16; ++kc) {
        bfrag8 ah0 = *(const bfrag8*)(Ahi + (size_t)m * 512 + kc * 32 + qd * 8);
        bfrag8 ah1 = *(const bfrag8*)(Ahi + (size_t)(16 + m) * 512 + kc * 32 + qd * 8);
        bfrag8 al0 = *(const bfrag8*)(Alo + (size_t)m * 512 + kc * 32 + qd * 8);
        bfrag8 al1 = *(const bfrag8*)(Alo + (size_t)(16 + m) * 512 + kc * 32 + qd * 8);
        size_t rb = ((size_t)(k * 64 + kc * 4 + qd) * 512 + g0 + m) * 8;
#pragma unroll
        for (int nt = 0; nt < 8; ++nt) {
            bfrag8 bh = *(const bfrag8*)(rfhi + rb + nt * 128);
            bfrag8 bl = *(const bfrag8*)(rflo + rb + nt * 128);
            acc[0][nt] = __builtin_amdgcn_mfma_f32_16x16x32_bf16(ah0, bh, acc[0][nt], 0, 0, 0);
            acc[0][nt] = __builtin_amdgcn_mfma_f32_16x16x32_bf16(ah0, bl, acc[0][nt], 0, 0, 0);
            acc[0][nt] = __builtin_amdgcn_mfma_f32_16x16x32_bf16(al0, bh, acc[0][nt], 0, 0, 0);
            acc[1][nt] = __builtin_amdgcn_mfma_f32_16x16x32_bf16(ah1, bh, acc[1][nt], 0, 0, 0);
            acc[1][nt] = __builtin_amdgcn_mfma_f32_16x16x32_bf16(ah1, bl, acc[1][nt], 0, 0, 0);
            acc[1][nt] = __builtin_amdgcn_mfma_f32_16x16x32_bf16(al1, bh, acc[1][nt], 0, 0, 0);
        }
    }
    const u16* hT = (const u16*)(ws + WFRAG_OFF);
    float* exc = ws + EXC_OFF;
#pragma unroll
    for (int mt = 0; mt < 2; ++mt)
#pragma unroll
        for (int nt = 0; nt < 8; ++nt)
#pragma unroll
            for (int reg = 0; reg < 4; ++reg) {
                int t = tt * 32 + mt * 16 + qd * 4 + reg;
                int g = g0 + nt * 16 + m;
                float hv = bf2f(hT[(size_t)(bb * 128 + t) * 2048 + k * 512 + g]);
                size_t o = (size_t)(bb * 128 + t) * 512 + g;
                float v = acc[mt][nt][reg] * hv;
                if (k == 0) exc[o] = v;
                else        exc[o] += v;
            }
}

// ---- excite stage 4: out = relu(excited) @ Wo^T + bo -----------------------
__global__ __launch_bounds__(256) void exciteO_kernel(
    const float* ws, const void* Wom, const void* bom, void* out) {
    int mode = ((const int*)ws)[0];
    __shared__ float S[8][512];
    int bb = blockIdx.x >> 4, tg = blockIdx.x & 15;
    const float* exc = ws + EXC_OFF + ((size_t)(bb * 128 + tg * 8)) * 512;
    int tid = threadIdx.x;
    for (int it = 0; it < 16; ++it) {
        int idx = it * 256 + tid;
        int tl = idx >> 9, g = idx & 511;
        S[tl][g] = fmaxf(exc[(size_t)tl * 512 + g], 0.f);
    }
    __syncthreads();
    int fo = tid & 63, tl0 = tid >> 6;
#pragma unroll
    for (int rep = 0; rep < 2; ++rep) {
        int tl = tl0 + rep * 4;
        float acc = 0.f;
        if (mode) {
            const uint4* wp = (const uint4*)((const u16*)Wom + (size_t)fo * HH);
            const float4* ev = (const float4*)S[tl];
#pragma unroll 8
            for (int it = 0; it < HH / 8; ++it) {
                uint4 qv = wp[it];
                float4 e0 = ev[2 * it], e1 = ev[2 * it + 1];
                float2 a0 = bf2x2(qv.x), a1 = bf2x2(qv.y), a2 = bf2x2(qv.z), a3 = bf2x2(qv.w);
                acc += a0.x * e0.x + a0.y * e0.y + a1.x * e0.z + a1.y * e0.w +
                       a2.x * e1.x + a2.y * e1.y + a3.x * e1.z + a3.y * e1.w;
            }
        } else {
            const float4* wp = (const float4*)((const float*)Wom + (size_t)fo * HH);
            const float4* ev = (const float4*)S[tl];
#pragma unroll 8
            for (int it = 0; it < HH / 4; ++it) {
                float4 qv = wp[it], e = ev[it];
                acc += qv.x * e.x + qv.y * e.y + qv.z * e.z + qv.w * e.w;
            }
        }
        acc += mode ? bf2f(((const u16*)bom)[fo]) : ((const float*)bom)[fo];
        int t = tg * 8 + tl;
        size_t oidx = ((size_t)bb * TS + t) * FF + fo;
        if (mode) ((u16*)out)[oidx] = f2bf_rne(acc);
        else      ((float*)out)[oidx] = acc;
    }
}

extern "C" void kernel_launch(void* const* d_in, const int* in_sizes, int n_in,
                              void* d_out, int out_size, void* d_ws, size_t ws_size,
                              hipStream_t stream) {
    const void* xin = d_in[0];
    const void* Wm  = d_in[1];
    const void* Zm  = d_in[2];
    const void* Um  = d_in[3];
    const void* Vm  = d_in[4];
    const void* Jm  = d_in[5];
    const void* bb  = d_in[6];
    const void* bnd = d_in[7];
    const void* Qm  = d_in[8];
    const void* Rm  = d_in[9];
    const void* Wo  = d_in[10];
    const void* bo  = d_in[11];
    float* ws = (float*)d_ws;

    initA_kernel<<<dim3(512), dim3(256), 0, stream>>>((const u16*)bnd, ws);
    initB_kernel<<<dim3(512), dim3(64), 0, stream>>>(xin, ws);
    prep_kernel<<<dim3(10240), dim3(256), 0, stream>>>(Wm, Zm, Um, Vm, ws);
    for (int tau = 0; tau < 2 * TS + LL - 2; ++tau) {   // 258 phases
        gemm_phase_kernel<<<dim3(768), dim3(256), 0, stream>>>(Wm, Zm, Um, Vm, bnd, ws, tau);
        gates_phase_kernel<<<dim3(256), dim3(256), 0, stream>>>(xin, Um, Jm, bb, bnd, ws, tau);
    }
    // ---- excite pipeline (all scratch overlays scan-dead regions) ----------
    fragprep_kernel<<<dim3(128), dim3(256), 0, stream>>>(Qm, ws, 2048, 0);
    fragprep_kernel<<<dim3(32), dim3(256), 0, stream>>>(Rm, ws, 512, 1);
    transpose_kernel<<<dim3(512), dim3(256), 0, stream>>>(ws);
    for (int k = 0; k < LL; ++k) {
        exciteR_kernel<<<dim3(256), dim3(256), 0, stream>>>(ws, k);
        exciteM_kernel<<<dim3(256), dim3(256), 0, stream>>>(ws, k);
    }
    exciteO_kernel<<<dim3(1024), dim3(256), 0, stream>>>(ws, Wo, bo, d_out);
}

// Round 5
// 4663.058 us; speedup vs baseline: 1.8666x; 1.2162x over previous
//
#include <hip/hip_runtime.h>
#include <hip/hip_bf16.h>

// ---------------------------------------------------------------------------
// StandardMRALSTM — round 10: R9 + excite-pipeline occupancy/coalescing fixes.
//  * R9 measured 5671us (excite rewrite -1.0ms). Residual excite pipeline
//    ~2.0ms vs ~0.3ms of work. Diagnosis (structural): transpose had 1024B
//    inter-lane read stride (64 lines/wave-load); exciteR/M ran at grid=256
//    = 1 wave/SIMD (zero TLP -> B-frag load latency on the MFMA chain).
//  * Fixes (bit-identical math, same accumulation order): LDS-tiled
//    transpose; exciteR grid 512 (bb x oct, acc[2][4]); exciteM grid 512
//    (bb x tt x gh, acc[2][4]); fragprep gc moved into grid (Q:512, R:128).
//  * Scan + memory map unchanged from R9 (passing, absmax 6.1e-5).
// ---------------------------------------------------------------------------

#define LL 4
#define HH 512
#define TS 128
#define GG 16
#define BB 64
#define FF 64
#define FIVE_H 2560
#define LBH (LL * BB * HH)

typedef unsigned short u16;
typedef unsigned int u32;
typedef unsigned long long u64;

typedef short bfrag8 __attribute__((ext_vector_type(8)));   // 8 bf16
typedef float facc4 __attribute__((ext_vector_type(4)));    // 4 fp32

#define SG_OFF    64
#define ZALL_OFF  1024
#define ZMASK_OFF 2048
#define C_OFF     4096
#define PING_OFF  (C_OFF + LBH)                       // 135168
#define PART_OFF  (PING_OFF + 2 * LBH)                // 397312
#define PART_SEG  (12 * 4 * HH * BB)                  // 1572864 floats per seg
#define HIST_OFF  (PART_OFF + 2 * PART_SEG)           // 3543040 (u16 region, 16.7M u16)
#define HFRAG_OFF (HIST_OFF + 8388608)                // 11931648 (u16 region)
#define WFRAG_OFF (HFRAG_OFF + 262144)                // 12193792 (u16 region, 20.97M u16)
// ---- excite-phase overlays (all scan-dead at excite time) ------------------
// hist_T  : u16[64b][128t][2048f]      at WFRAG_OFF       (16777216 u16)
// Qfrag hi: u16[4k][256fb][512h][8]    at WFRAG_OFF+16777216 u16 (4194304 u16)
// Qfrag lo: u16 same                   at PART_OFF        (4194304 u16)
// Rfrag hi: u16[4k][64hb][512g][8]     at PART_OFF+4194304 u16   (1048576 u16)
// Rfrag lo: u16 same                   at +1048576 u16    (ends exactly at HIST_OFF)
// r hi    : u16[64b][128t][512h]       at HIST_OFF        (4194304 u16)
// r lo    : u16 same                   at +4194304 u16
// excited : f32[8192bt][512g]          at HIST_OFF+4194304 floats (ends at HFRAG_OFF)
#define EXC_OFF   (HIST_OFF + 4194304)                // 7737344 floats

__device__ __forceinline__ float bf2f(u16 u) { return __uint_as_float(((u32)u) << 16); }
__device__ __forceinline__ float2 bf2x2(u32 u) {
    float2 r;
    r.x = __uint_as_float(u << 16);
    r.y = __uint_as_float(u & 0xFFFF0000u);
    return r;
}
__device__ __forceinline__ u16 f2bf_rne(float f) {
    u32 x = __float_as_uint(f);
    return (u16)((x + 0x7FFFu + ((x >> 16) & 1u)) >> 16);
}
__device__ __forceinline__ float sigm(float x) { return 1.f / (1.f + expf(-x)); }

template <bool BF>
__device__ __forceinline__ float ldv(const void* p, size_t i) {
    return BF ? bf2f(((const u16*)p)[i]) : ((const float*)p)[i];
}

template <bool BF>
__device__ __forceinline__ float dot16(const void* row, const float* xs) {
    float s = 0.f;
    if (BF) {
        const uint4* p = (const uint4*)row;
        uint4 a = p[0], b4 = p[1];
        float2 v;
        v = bf2x2(a.x);  s += v.x * xs[0]  + v.y * xs[1];
        v = bf2x2(a.y);  s += v.x * xs[2]  + v.y * xs[3];
        v = bf2x2(a.z);  s += v.x * xs[4]  + v.y * xs[5];
        v = bf2x2(a.w);  s += v.x * xs[6]  + v.y * xs[7];
        v = bf2x2(b4.x); s += v.x * xs[8]  + v.y * xs[9];
        v = bf2x2(b4.y); s += v.x * xs[10] + v.y * xs[11];
        v = bf2x2(b4.z); s += v.x * xs[12] + v.y * xs[13];
        v = bf2x2(b4.w); s += v.x * xs[14] + v.y * xs[15];
    } else {
        const float4* p = (const float4*)row;
#pragma unroll
        for (int i = 0; i < 4; ++i) {
            float4 v = p[i];
            s += v.x * xs[4 * i] + v.y * xs[4 * i + 1] + v.z * xs[4 * i + 2] + v.w * xs[4 * i + 3];
        }
    }
    return s;
}

// ---- init A ----------------------------------------------------------------
__global__ void initA_kernel(const u16* __restrict__ bnd_raw, float* __restrict__ ws) {
    size_t i = (size_t)blockIdx.x * 256 + threadIdx.x;
    if (i < LBH) ws[C_OFF + i] = 0.f;
    if (i < 512) ws[SG_OFF + i] = 0.f;
    if (i == 0) {
        int bf = 1;
        for (int j = 0; j < 32; ++j) {
            float v = bf2f(bnd_raw[2 * j]);
            if (!(v >= 0.f && v <= 1.f)) bf = 0;
        }
        ((int*)ws)[0] = bf;
    }
}

// ---- init B ----------------------------------------------------------------
template <bool BF>
__device__ void initB_body(const void* xin, float* ws) {
    int tk = blockIdx.x;
    int t = tk >> 2, k = tk & 3;
    int b = threadIdx.x;
    bool z = false;
    size_t base = (size_t)b * TS * FF + (size_t)t * FF + k * GG;
#pragma unroll
    for (int g = 0; g < GG; ++g) {
        float v = ldv<BF>(xin, base + g);
        z |= !(v != v);
    }
    u64 m = __ballot(z);
    if (b == 0) {
        ((u64*)(ws + ZMASK_OFF))[tk] = m;
        ((int*)(ws + ZALL_OFF))[tk] = (m == ~0ull) ? 1 : 0;
    }
}
__global__ __launch_bounds__(64) void initB_kernel(const void* xin, float* ws) {
    int mode = ((const int*)ws)[0];
    if (mode) initB_body<true>(xin, ws);
    else      initB_body<false>(xin, ws);
}

// ---- weight prep (BF mode only): reorder into A-fragment layout ------------
__global__ __launch_bounds__(256) void prep_kernel(
    const void* Wm, const void* Zm, const void* Um, const void* Vm, float* ws) {
    if (((const int*)ws)[0] == 0) return;   // fp32 mode: no prep
    int gw = (int)((blockIdx.x * 256 + threadIdx.x) >> 6);   // matlayer*2560 + r
    int lane = threadIdx.x & 63;
    int ml = gw / 2560, r = gw - ml * 2560;
    int mi = ml >> 2, k = ml & 3;
    int RS = (mi == 2) ? (HH + GG) : HH;
    const void* M = (mi == 0) ? Wm : (mi == 1) ? Zm : (mi == 2) ? Um : Vm;
    const u16* src = (const u16*)M + (size_t)k * FIVE_H * RS + (size_t)r * RS + lane * 8;
    uint4 v = *(const uint4*)src;
    int q = lane >> 4, kb = (lane >> 2) & 3, qd = lane & 3;
    int slab = r >> 6, wv = (r >> 4) & 3, m = r & 15;
    u16* dst = (u16*)(ws + WFRAG_OFF) + (size_t)ml * (2560 * 512)
             + ((((size_t)(slab * 4 + q) * 4 + wv) * 4 + kb) * 64 + (qd * 16 + m)) * 8;
    *(uint4*)dst = v;
}

// ---- per-phase metadata ----------------------------------------------------
template <bool BF>
__device__ __forceinline__ void phase_meta(const void* bnd, const float* ws,
                                           int tau, int s,
                                           int& t, int& k, int& mcase, int& azf, int& nblk) {
    k = (tau & 1) + 2 * s;
    t = (tau - k) >> 1;
    mcase = 4; azf = 0; nblk = 0;
    if (t < 0 || t >= TS) { t = -1; return; }
    const float* sgsum = ws + SG_OFF;
    bool p_hi = (t == 0) ? (ldv<BF>(bnd, (size_t)k * TS) > 0.5f) : (sgsum[(t - 1) * 4 + k] > 16384.f);
    bool l_hi = (k == 0) ? (ldv<BF>(bnd, (size_t)t) > 0.5f) : (sgsum[t * 4 + (k - 1)] > 16384.f);
    mcase = p_hi ? (l_hi ? 3 : 2) : (l_hi ? 1 : 4);
    azf = ((const int*)(ws + ZALL_OFF))[t * 4 + k] ? 0 : 1;
    if (mcase == 4) return;
    int gs = (mcase == 1) ? 0 : 1, ng = 4 - gs;
    int nW = (t > 0) ? ng : 0;
    int nU = ((mcase == 1 || mcase == 3) && k > 0) ? ng : 0;
    int nV = azf ? nU : 0;
    nblk = (nW + nU + nV) * 32;
}

// ---- unit -> (matrix, gate) routing ----------------------------------------
struct SlotInfo {
    const u16* M16; const float* Mf; int RS; int path; int g;
    const float* hv;
};
template <bool BF>
__device__ __forceinline__ SlotInfo slot_info(
    const void* Wm, const void* Zm, const void* Um, const void* Vm,
    const float* ws, int unit, int t, int k, int mcase) {
    int gs = (mcase == 1) ? 0 : 1, ng = 4 - gs;
    int nW = (t > 0) ? ng : 0;
    int nU = ((mcase == 1 || mcase == 3) && k > 0) ? ng : 0;
    int mat, g;
    if (unit < nW)            { mat = (mcase == 1) ? 0 : 1; g = gs + unit; }
    else if (unit < nW + nU)  { mat = 2; g = gs + unit - nW; }
    else                      { mat = 3; g = gs + unit - nW - nU; }
    const void* M = (mat == 0) ? Wm : (mat == 1) ? Zm : (mat == 2) ? Um : Vm;
    int kn = (k + 1 < LL) ? k + 1 : LL - 1;
    const float* ping = ws + PING_OFF;
    const float* prev = ping + (size_t)((t + 1) & 1) * LBH;   // [k][c][b]
    const float* cur  = ping + (size_t)(t & 1) * LBH;
    SlotInfo si;
    si.M16 = (const u16*)M; si.Mf = (const float*)M;
    si.RS = (mat == 2) ? (HH + GG) : HH;
    si.path = (mat <= 1) ? 0 : (mat == 2 ? 1 : 2);
    si.g = g;
    si.hv = (mat == 0) ? prev + (size_t)k * HH * BB
          : (mat == 1) ? prev + (size_t)kn * HH * BB
                       : cur + (size_t)(k - 1) * HH * BB;
    return si;
}

// ---- MFMA gemm slot (BF mode): LDS-free, fragment-resident -----------------
__device__ void gemm_slot_bf(float* ws, int seg, int idx, int t, int k, int mcase) {
    int tid = threadIdx.x;
    int q = idx & 3, sub = (idx >> 2) & 7, unit = idx >> 5;
    int gs = (mcase == 1) ? 0 : 1, ng = 4 - gs;
    int nW = (t > 0) ? ng : 0;
    int nU = ((mcase == 1 || mcase == 3) && k > 0) ? ng : 0;
    int mat, g;
    if (unit < nW)            { mat = (mcase == 1) ? 0 : 1; g = gs + unit; }
    else if (unit < nW + nU)  { mat = 2; g = gs + unit - nW; }
    else                      { mat = 3; g = gs + unit - nW - nU; }
    int path = (mat <= 1) ? 0 : (mat == 2 ? 1 : 2);
    int slab = (g < 3) ? g * 8 + sub : 32 + sub;

    int lb, par;
    if (mat == 0)      { lb = k;  par = (t + 1) & 1; }
    else if (mat == 1) { lb = (k + 1 < LL) ? k + 1 : LL - 1; par = (t + 1) & 1; }
    else               { lb = k - 1; par = t & 1; }

    int lane = tid & 63, wave = tid >> 6;
    int m = lane & 15, qd = lane >> 4;

    const u16* af = (const u16*)(ws + WFRAG_OFF)
                  + (size_t)(mat * 4 + k) * (2560 * 512)
                  + (size_t)(slab * 4 + q) * 8192 + wave * 2048 + lane * 8;
    const u16* hf = (const u16*)(ws + HFRAG_OFF) + (size_t)((par * 4 + lb) * 2) * 32768;

    facc4 acc[4];
#pragma unroll
    for (int i = 0; i < 4; ++i) acc[i] = (facc4){0.f, 0.f, 0.f, 0.f};
#pragma unroll
    for (int kb = 0; kb < 4; ++kb) {
        bfrag8 a = *(const bfrag8*)(af + kb * 512);
        size_t hbk = (size_t)(q * 16 + kb * 4 + qd) * 512 + m * 8;
#pragma unroll
        for (int bg = 0; bg < 4; ++bg) {
            bfrag8 bh = *(const bfrag8*)(hf + hbk + bg * 128);
            bfrag8 bl = *(const bfrag8*)(hf + 32768 + hbk + bg * 128);
            acc[bg] = __builtin_amdgcn_mfma_f32_16x16x32_bf16(a, bh, acc[bg], 0, 0, 0);
            acc[bg] = __builtin_amdgcn_mfma_f32_16x16x32_bf16(a, bl, acc[bg], 0, 0, 0);
        }
    }
    float* pout = ws + PART_OFF + (size_t)seg * PART_SEG +
                  ((size_t)(path * 4 + q) * 4 + g) * (size_t)HH * BB;
#pragma unroll
    for (int bg = 0; bg < 4; ++bg)
#pragma unroll
        for (int reg = 0; reg < 4; ++reg)
            pout[(size_t)(sub * 64 + wave * 16 + qd * 4 + reg) * BB + bg * 16 + m] = acc[bg][reg];
}

// ---- fp32 gemm slot (ACTIVE path, R4-proven) -------------------------------
__device__ void gemm_slot_f32(const void* Wm, const void* Zm, const void* Um, const void* Vm,
                              float* ws, float* wt, float* ht,
                              int seg, int idx, int t, int k, int mcase) {
    int tid = threadIdx.x;
    int q = idx & 3, sub = (idx >> 2) & 7, unit = idx >> 5;
    SlotInfo si = slot_info<false>(Wm, Zm, Um, Vm, ws, unit, t, k, mcase);
    int gbase = (si.g < 3) ? si.g * 512 : 2048;
    size_t mbase = (size_t)k * FIVE_H * si.RS + (size_t)(gbase + sub * 64) * si.RS + q * 128;

    int rg = tid >> 4, bg = tid & 15;
    float acc[4][4] = {{0.f}};
    for (int half = 0; half < 2; ++half) {
        int sr = tid >> 2, scg = (tid & 3) * 16;
        size_t rowoff = mbase + (size_t)sr * si.RS + half * 64 + scg;
#pragma unroll
        for (int i = 0; i < 4; ++i)
            *(float4*)&wt[sr * 68 + scg + 4 * i] = *(const float4*)(si.Mf + rowoff + 4 * i);
        int hc = tid >> 2, hb = (tid & 3) * 16;
        const float* hrow = si.hv + (size_t)(q * 128 + half * 64 + hc) * BB + hb;
#pragma unroll
        for (int i = 0; i < 4; ++i)
            *(float4*)&ht[hc * 68 + hb + 4 * i] = *(const float4*)(hrow + 4 * i);
        __syncthreads();
#pragma unroll 4
        for (int kk4 = 0; kk4 < 64; kk4 += 4) {
            float w[4][4], h[4][4];
#pragma unroll
            for (int j = 0; j < 4; ++j)
                *(float4*)w[j] = *(const float4*)&wt[(rg * 4 + j) * 68 + kk4];
#pragma unroll
            for (int j = 0; j < 4; ++j)
                *(float4*)h[j] = *(const float4*)&ht[(kk4 + j) * 68 + bg * 4];
#pragma unroll
            for (int rj = 0; rj < 4; ++rj)
#pragma unroll
                for (int bj = 0; bj < 4; ++bj)
#pragma unroll
                    for (int j = 0; j < 4; ++j)
                        acc[rj][bj] += w[rj][j] * h[j][bj];
        }
        __syncthreads();
    }
    float* pout = ws + PART_OFF + (size_t)seg * PART_SEG +
                  ((size_t)(si.path * 4 + q) * 4 + si.g) * (size_t)HH * BB;
#pragma unroll
    for (int rj = 0; rj < 4; ++rj) {
        float4 vv = make_float4(acc[rj][0], acc[rj][1], acc[rj][2], acc[rj][3]);
        *(float4*)&pout[(size_t)(sub * 64 + rg * 4 + rj) * BB + bg * 4] = vv;
    }
}

__global__ __launch_bounds__(256) void gemm_phase_kernel(
    const void* Wm, const void* Zm, const void* Um, const void* Vm,
    const void* bnd, float* ws, int tau) {
    __shared__ __align__(16) u16 gsm[26112];
    int mode = ((const int*)ws)[0];
    if (mode) {
        int t0, k0, m0, a0, n0, t1, k1, m1, a1, n1;
        phase_meta<true>(bnd, ws, tau, 0, t0, k0, m0, a0, n0);
        phase_meta<true>(bnd, ws, tau, 1, t1, k1, m1, a1, n1);
        int bid = blockIdx.x;
        if (bid < n0)           gemm_slot_bf(ws, 0, bid, t0, k0, m0);
        else if (bid < n0 + n1) gemm_slot_bf(ws, 1, bid - n0, t1, k1, m1);
    } else {
        float* fs = (float*)gsm;
        int t0, k0, m0, a0, n0, t1, k1, m1, a1, n1;
        phase_meta<false>(bnd, ws, tau, 0, t0, k0, m0, a0, n0);
        phase_meta<false>(bnd, ws, tau, 1, t1, k1, m1, a1, n1);
        int bid = blockIdx.x;
        if (bid < n0)           gemm_slot_f32(Wm, Zm, Um, Vm, ws, fs, fs + 4352, 0, bid, t0, k0, m0);
        else if (bid < n0 + n1) gemm_slot_f32(Wm, Zm, Um, Vm, ws, fs, fs + 4352, 1, bid - n0, t1, k1, m1);
    }
}

// ---- gates slot (R2-proven) ------------------------------------------------
template <bool BF>
__device__ void gates_slot(const void* xin, const void* Um, const void* Jm,
                           const void* bbias, float* ws, float* smem,
                           int seg, int jblk, int t, int k, int mcase, int azf) {
    float (*xs)[GG + 1] = (float (*)[GG + 1])smem;
    float* red = smem + BB * (GG + 1);
    int tid = threadIdx.x;
    int j = jblk * 4 + (tid >> 6);
    int b = tid & 63;

    {
        int b2 = tid >> 2, i0 = (tid & 3) * 4;
#pragma unroll
        for (int i = 0; i < 4; ++i) {
            float v = ldv<BF>(xin, (size_t)b2 * TS * FF + (size_t)t * FF + k * GG + i0 + i);
            xs[b2][i0 + i] = (v != v) ? 0.f : v;
        }
    }
    __syncthreads();
    u64 zm = ((const u64*)(ws + ZMASK_OFF))[t * 4 + k];
    bool zb = (zm >> b) & 1ull;

    float* cbuf = ws + C_OFF;
    const float* part = ws + PART_OFF + (size_t)seg * PART_SEG;
    float* cur = ws + PING_OFF + (size_t)(t & 1) * LBH;
    const float* prev = ws + PING_OFF + (size_t)((t + 1) & 1) * LBH;
    u16* hist = (u16*)(ws + HIST_OFF);
    size_t sidx = ((size_t)k * HH + j) * BB + b;

    float hn, sgv;
    if (mcase == 4) {
        float c = cbuf[sidx];
        float o = sigm(ldv<BF>(bbias, (size_t)k * FIVE_H + 1536 + j));
        hn = o * tanhf(c);
        float bsg = ldv<BF>(bbias, (size_t)k * FIVE_H + 2048 + j);
        sgv = fminf(fmaxf((bsg + 1.f) * 0.5f, 0.f), 1.f);
    } else {
        bool hasWZ = (t > 0);
        bool hasU = (k > 0) && (mcase != 2);
        const float* xv = &xs[b][0];
        auto psum = [&](int path, int g) -> float {
            float s = 0.f;
#pragma unroll
            for (int qq = 0; qq < 4; ++qq)
                s += part[(((size_t)(path * 4 + qq) * 4 + g) * HH + j) * BB + b];
            return s;
        };
        auto pre = [&](int g) -> float {
            int gb = (g < 3) ? g * 512 : 2048;
            float s = ldv<BF>(bbias, (size_t)k * FIVE_H + gb + j);
            if (hasWZ) s += psum(0, g);
            if (mcase == 2) {
                if (zb) {
                    const void* row = BF ? (const void*)((const u16*)Jm + (size_t)k * FIVE_H * GG + (size_t)(gb + j) * GG)
                                         : (const void*)((const float*)Jm + (size_t)k * FIVE_H * GG + (size_t)(gb + j) * GG);
                    s += dot16<BF>(row, xv);
                }
            } else {
                if (zb) {
                    if (hasU) s += psum(1, g);
                    const void* row = BF ? (const void*)((const u16*)Um + (size_t)k * FIVE_H * (HH + GG) + (size_t)(gb + j) * (HH + GG) + HH)
                                         : (const void*)((const float*)Um + (size_t)k * FIVE_H * (HH + GG) + (size_t)(gb + j) * (HH + GG) + HH);
                    s += dot16<BF>(row, xv);
                } else {
                    if (hasU && azf) s += psum(2, g);
                }
            }
            return s;
        };
        float preg = pre(1), prei = pre(2), presg = pre(3);
        float gg = tanhf(preg), ii = sigm(prei);
        float cnew;
        if (mcase == 1) {
            float f = sigm(pre(0));
            cnew = f * cbuf[sidx] + ii * gg;
        } else {
            cnew = ii * gg;
        }
        cbuf[sidx] = cnew;
        hn = (t > 0) ? prev[sidx] : 0.f;
        sgv = fminf(fmaxf((presg + 1.f) * 0.5f, 0.f), 1.f);
    }
    cur[sidx] = hn;
    u16 hi = f2bf_rne(hn);
    hist[((size_t)(t * 4 + k) * HH + j) * BB + b] = hi;
    if (BF) {
        u16 lo = f2bf_rne(hn - bf2f(hi));
        u16* hfw = (u16*)(ws + HFRAG_OFF) + (size_t)(((t & 1) * 4 + k) * 2) * 32768;
        size_t fo = ((size_t)(j >> 3) * 64 + b) * 8 + (j & 7);
        hfw[fo] = hi;
        hfw[32768 + fo] = lo;
    }

    float s = sgv;
#pragma unroll
    for (int off = 32; off > 0; off >>= 1) s += __shfl_down(s, off);
    if ((tid & 63) == 0) red[tid >> 6] = s;
    __syncthreads();
    if (tid == 0)
        atomicAdd(&ws[SG_OFF + t * 4 + k], red[0] + red[1] + red[2] + red[3]);
}

template <bool BF>
__device__ void gates_phase_body(const void* xin, const void* Um, const void* Jm,
                                 const void* bbias, const void* bnd, float* ws,
                                 float* smem, int tau) {
    int seg = blockIdx.x >> 7, jblk = blockIdx.x & 127;
    int t, k, mc, az, nb;
    phase_meta<BF>(bnd, ws, tau, seg, t, k, mc, az, nb);
    if (t >= 0)
        gates_slot<BF>(xin, Um, Jm, bbias, ws, smem, seg, jblk, t, k, mc, az);
}
__global__ __launch_bounds__(256) void gates_phase_kernel(
    const void* xin, const void* Um, const void* Jm, const void* bbias,
    const void* bnd, float* ws, int tau) {
    __shared__ float smem[BB * (GG + 1) + 4];
    int mode = ((const int*)ws)[0];
    if (mode) gates_phase_body<true>(xin, Um, Jm, bbias, bnd, ws, smem, tau);
    else      gates_phase_body<false>(xin, Um, Jm, bbias, bnd, ws, smem, tau);
}

// ---- excite stage 0: fragment prep for Q (which=0) / R (which=1) -----------
// grid = (ko*nfg + fg)*4 + gc ; one 64f x 128n tile per block.
template <bool BF>
__device__ void fragprep_body(const void* src, float* ws, int Fext, int which) {
    int tid = threadIdx.x;
    int nfg = Fext >> 6;
    int gc = blockIdx.x & 3;
    int bo = blockIdx.x >> 2;
    int ko = bo / nfg, fg = bo % nfg;
    size_t kstride = (size_t)Fext * 512;
    u16 *dhi, *dlo;
    if (which == 0) { dhi = (u16*)(ws + WFRAG_OFF) + 16777216; dlo = (u16*)(ws + PART_OFF); }
    else            { dhi = (u16*)(ws + PART_OFF) + 4194304;   dlo = dhi + 1048576; }
    __shared__ float S[64][129];
    for (int it = 0; it < 32; ++it) {
        int idx = it * 256 + tid;
        int f = idx >> 7, n = idx & 127;
        S[f][n] = ldv<BF>(src, ko * kstride + (size_t)(fg * 64 + f) * 512 + gc * 128 + n);
    }
    __syncthreads();
    for (int it = 0; it < 4; ++it) {
        int idx = it * 256 + tid;
        int fbl = idx >> 7, n = idx & 127;
        u32 hiw[4], low[4];
#pragma unroll
        for (int jp = 0; jp < 4; ++jp) {
            float v0 = S[fbl * 8 + 2 * jp][n], v1 = S[fbl * 8 + 2 * jp + 1][n];
            u16 h0 = f2bf_rne(v0), h1 = f2bf_rne(v1);
            u16 l0 = f2bf_rne(v0 - bf2f(h0)), l1 = f2bf_rne(v1 - bf2f(h1));
            hiw[jp] = (u32)h0 | ((u32)h1 << 16);
            low[jp] = (u32)l0 | ((u32)l1 << 16);
        }
        size_t o = (((size_t)ko * (Fext >> 3) + fg * 8 + fbl) * 512 + gc * 128 + n) * 8;
        *(uint4*)(dhi + o) = make_uint4(hiw[0], hiw[1], hiw[2], hiw[3]);
        *(uint4*)(dlo + o) = make_uint4(low[0], low[1], low[2], low[3]);
    }
}
__global__ __launch_bounds__(256) void fragprep_kernel(const void* src, float* ws,
                                                       int Fext, int which) {
    int mode = ((const int*)ws)[0];
    if (mode) fragprep_body<true>(src, ws, Fext, which);
    else      fragprep_body<false>(src, ws, Fext, which);
}

// ---- excite stage 1: hist [tk][j][b] -> hist_T [b][t][f=k*512+j] -----------
// LDS-tiled: coalesced 128B row reads; 128B-contiguous-per-4-lane writes.
__global__ __launch_bounds__(256) void transpose_kernel(float* ws) {
    int tk = blockIdx.x;
    int t = tk >> 2, k = tk & 3;
    const u16* hist = (const u16*)(ws + HIST_OFF);
    u16* hT = (u16*)(ws + WFRAG_OFF);
    __shared__ u16 T[64][72];
    int tid = threadIdx.x;
    for (int j0 = 0; j0 < 512; j0 += 64) {
        int jl = tid >> 3, b0 = (tid & 7) * 8;
        *(uint4*)&T[jl][b0]      = *(const uint4*)&hist[((size_t)tk * 512 + j0 + jl) * 64 + b0];
        *(uint4*)&T[jl + 32][b0] = *(const uint4*)&hist[((size_t)tk * 512 + j0 + jl + 32) * 64 + b0];
        __syncthreads();
        int b = tid >> 2, jj0 = (tid & 3) * 16;
        u16 tmp[16];
#pragma unroll
        for (int i = 0; i < 16; ++i) tmp[i] = T[jj0 + i][b];
        u16* dst = &hT[((size_t)(b * 128 + t)) * 2048 + k * 512 + j0 + jj0];
        *(uint4*)&dst[0] = *(uint4*)&tmp[0];
        *(uint4*)&dst[8] = *(uint4*)&tmp[8];
        __syncthreads();
    }
}

// ---- excite stage 2 (per k): r = sigmoid(h_cat @ Q[k]), split hi/lo --------
// grid 512 = bb(64) x oct(8); wave: 32 t-rows x 64 h-cols, acc[2][4].
__global__ __launch_bounds__(256) void exciteR_kernel(float* ws, int k) {
    int tid = threadIdx.x, lane = tid & 63, w = tid >> 6;
    int m = lane & 15, qd = lane >> 4;
    int bb = blockIdx.x >> 3, oct = blockIdx.x & 7;
    int h0 = oct * 64;
    const u16* hT = (const u16*)(ws + WFRAG_OFF);
    const u16* qhi = hT + 16777216;
    const u16* qlo = (const u16*)(ws + PART_OFF);
    const u16* A = hT + (size_t)(bb * 128 + w * 32) * 2048;

    facc4 acc[2][4];
#pragma unroll
    for (int i = 0; i < 2; ++i)
#pragma unroll
        for (int j = 0; j < 4; ++j) acc[i][j] = (facc4){0.f, 0.f, 0.f, 0.f};

    for (int kc = 0; kc < 64; ++kc) {
        bfrag8 a0 = *(const bfrag8*)(A + (size_t)m * 2048 + kc * 32 + qd * 8);
        bfrag8 a1 = *(const bfrag8*)(A + (size_t)(16 + m) * 2048 + kc * 32 + qd * 8);
        size_t qb = ((size_t)(k * 256 + kc * 4 + qd) * 512 + h0 + m) * 8;
#pragma unroll
        for (int nt = 0; nt < 4; ++nt) {
            bfrag8 bh = *(const bfrag8*)(qhi + qb + nt * 128);
            bfrag8 bl = *(const bfrag8*)(qlo + qb + nt * 128);
            acc[0][nt] = __builtin_amdgcn_mfma_f32_16x16x32_bf16(a0, bh, acc[0][nt], 0, 0, 0);
            acc[0][nt] = __builtin_amdgcn_mfma_f32_16x16x32_bf16(a0, bl, acc[0][nt], 0, 0, 0);
            acc[1][nt] = __builtin_amdgcn_mfma_f32_16x16x32_bf16(a1, bh, acc[1][nt], 0, 0, 0);
            acc[1][nt] = __builtin_amdgcn_mfma_f32_16x16x32_bf16(a1, bl, acc[1][nt], 0, 0, 0);
        }
    }
    u16* rhi = (u16*)(ws + HIST_OFF);
    u16* rlo = rhi + 4194304;
#pragma unroll
    for (int mt = 0; mt < 2; ++mt)
#pragma unroll
        for (int nt = 0; nt < 4; ++nt)
#pragma unroll
            for (int reg = 0; reg < 4; ++reg) {
                float rv = sigm(acc[mt][nt][reg]);
                int t = w * 32 + mt * 16 + qd * 4 + reg;
                int h = h0 + nt * 16 + m;
                size_t o = (size_t)(bb * 128 + t) * 512 + h;
                u16 hi = f2bf_rne(rv);
                rhi[o] = hi;
                rlo[o] = f2bf_rne(rv - bf2f(hi));
            }
}

// ---- excite stage 3 (per k): mul1 = r @ R[k]; excited += mul1 * h ----------
// grid 512 = bb(64) x tt(4) x gh(2); wave: 32 t-rows x 64 g-cols, acc[2][4].
__global__ __launch_bounds__(256) void exciteM_kernel(float* ws, int k) {
    int tid = threadIdx.x, lane = tid & 63, w = tid >> 6;
    int m = lane & 15, qd = lane >> 4;
    int bb = blockIdx.x >> 3, tt = (blockIdx.x >> 1) & 3, gh = blockIdx.x & 1;
    int g0 = gh * 256 + w * 64;
    const u16* rhi = (const u16*)(ws + HIST_OFF);
    const u16* rlo = rhi + 4194304;
    const u16* rfhi = (const u16*)(ws + PART_OFF) + 4194304;
    const u16* rflo = rfhi + 1048576;
    const u16* Ahi = rhi + (size_t)(bb * 128 + tt * 32) * 512;
    const u16* Alo = rlo + (size_t)(bb * 128 + tt * 32) * 512;

    facc4 acc[2][4];
#pragma unroll
    for (int i = 0; i < 2; ++i)
#pragma unroll
        for (int j = 0; j < 4; ++j) acc[i][j] = (facc4){0.f, 0.f, 0.f, 0.f};

    for (int kc = 0; kc < 16; ++kc) {
        bfrag8 ah0 = *(const bfrag8*)(Ahi + (size_t)m * 512 + kc * 32 + qd * 8);
        bfrag8 ah1 = *(const bfrag8*)(Ahi + (size_t)(16 + m) * 512 + kc * 32 + qd * 8);
        bfrag8 al0 = *(const bfrag8*)(Alo + (size_t)m * 512 + kc * 32 + qd * 8);
        bfrag8 al1 = *(const bfrag8*)(Alo + (size_t)(16 + m) * 512 + kc * 32 + qd * 8);
        size_t rb = ((size_t)(k * 64 + kc * 4 + qd) * 512 + g0 + m) * 8;
#pragma unroll
        for (int nt = 0; nt < 4; ++nt) {
            bfrag8 bh = *(const bfrag8*)(rfhi + rb + nt * 128);
            bfrag8 bl = *(const bfrag8*)(rflo + rb + nt * 128);
            acc[0][nt] = __builtin_amdgcn_mfma_f32_16x16x32_bf16(ah0, bh, acc[0][nt], 0, 0, 0);
            acc[0][nt] = __builtin_amdgcn_mfma_f32_16x16x32_bf16(ah0, bl, acc[0][nt], 0, 0, 0);
            acc[0][nt] = __builtin_amdgcn_mfma_f32_16x16x32_bf16(al0, bh, acc[0][nt], 0, 0, 0);
            acc[1][nt] = __builtin_amdgcn_mfma_f32_16x16x32_bf16(ah1, bh, acc[1][nt], 0, 0, 0);
            acc[1][nt] = __builtin_amdgcn_mfma_f32_16x16x32_bf16(ah1, bl, acc[1][nt], 0, 0, 0);
            acc[1][nt] = __builtin_amdgcn_mfma_f32_16x16x32_bf16(al1, bh, acc[1][nt], 0, 0, 0);
        }
    }
    const u16* hT = (const u16*)(ws + WFRAG_OFF);
    float* exc = ws + EXC_OFF;
#pragma unroll
    for (int mt = 0; mt < 2; ++mt)
#pragma unroll
        for (int nt = 0; nt < 4; ++nt)
#pragma unroll
            for (int reg = 0; reg < 4; ++reg) {
                int t = tt * 32 + mt * 16 + qd * 4 + reg;
                int g = g0 + nt * 16 + m;
                float hv = bf2f(hT[(size_t)(bb * 128 + t) * 2048 + k * 512 + g]);
                size_t o = (size_t)(bb * 128 + t) * 512 + g;
                float v = acc[mt][nt][reg] * hv;
                if (k == 0) exc[o] = v;
                else        exc[o] += v;
            }
}

// ---- excite stage 4: out = relu(excited) @ Wo^T + bo -----------------------
__global__ __launch_bounds__(256) void exciteO_kernel(
    const float* ws, const void* Wom, const void* bom, void* out) {
    int mode = ((const int*)ws)[0];
    __shared__ float S[8][512];
    int bb = blockIdx.x >> 4, tg = blockIdx.x & 15;
    const float* exc = ws + EXC_OFF + ((size_t)(bb * 128 + tg * 8)) * 512;
    int tid = threadIdx.x;
    for (int it = 0; it < 16; ++it) {
        int idx = it * 256 + tid;
        int tl = idx >> 9, g = idx & 511;
        S[tl][g] = fmaxf(exc[(size_t)tl * 512 + g], 0.f);
    }
    __syncthreads();
    int fo = tid & 63, tl0 = tid >> 6;
#pragma unroll
    for (int rep = 0; rep < 2; ++rep) {
        int tl = tl0 + rep * 4;
        float acc = 0.f;
        if (mode) {
            const uint4* wp = (const uint4*)((const u16*)Wom + (size_t)fo * HH);
            const float4* ev = (const float4*)S[tl];
#pragma unroll 8
            for (int it = 0; it < HH / 8; ++it) {
                uint4 qv = wp[it];
                float4 e0 = ev[2 * it], e1 = ev[2 * it + 1];
                float2 a0 = bf2x2(qv.x), a1 = bf2x2(qv.y), a2 = bf2x2(qv.z), a3 = bf2x2(qv.w);
                acc += a0.x * e0.x + a0.y * e0.y + a1.x * e0.z + a1.y * e0.w +
                       a2.x * e1.x + a2.y * e1.y + a3.x * e1.z + a3.y * e1.w;
            }
        } else {
            const float4* wp = (const float4*)((const float*)Wom + (size_t)fo * HH);
            const float4* ev = (const float4*)S[tl];
#pragma unroll 8
            for (int it = 0; it < HH / 4; ++it) {
                float4 qv = wp[it], e = ev[it];
                acc += qv.x * e.x + qv.y * e.y + qv.z * e.z + qv.w * e.w;
            }
        }
        acc += mode ? bf2f(((const u16*)bom)[fo]) : ((const float*)bom)[fo];
        int t = tg * 8 + tl;
        size_t oidx = ((size_t)bb * TS + t) * FF + fo;
        if (mode) ((u16*)out)[oidx] = f2bf_rne(acc);
        else      ((float*)out)[oidx] = acc;
    }
}

extern "C" void kernel_launch(void* const* d_in, const int* in_sizes, int n_in,
                              void* d_out, int out_size, void* d_ws, size_t ws_size,
                              hipStream_t stream) {
    const void* xin = d_in[0];
    const void* Wm  = d_in[1];
    const void* Zm  = d_in[2];
    const void* Um  = d_in[3];
    const void* Vm  = d_in[4];
    const void* Jm  = d_in[5];
    const void* bb  = d_in[6];
    const void* bnd = d_in[7];
    const void* Qm  = d_in[8];
    const void* Rm  = d_in[9];
    const void* Wo  = d_in[10];
    const void* bo  = d_in[11];
    float* ws = (float*)d_ws;

    initA_kernel<<<dim3(512), dim3(256), 0, stream>>>((const u16*)bnd, ws);
    initB_kernel<<<dim3(512), dim3(64), 0, stream>>>(xin, ws);
    prep_kernel<<<dim3(10240), dim3(256), 0, stream>>>(Wm, Zm, Um, Vm, ws);
    for (int tau = 0; tau < 2 * TS + LL - 2; ++tau) {   // 258 phases
        gemm_phase_kernel<<<dim3(768), dim3(256), 0, stream>>>(Wm, Zm, Um, Vm, bnd, ws, tau);
        gates_phase_kernel<<<dim3(256), dim3(256), 0, stream>>>(xin, Um, Jm, bb, bnd, ws, tau);
    }
    // ---- excite pipeline (all scratch overlays scan-dead regions) ----------
    fragprep_kernel<<<dim3(512), dim3(256), 0, stream>>>(Qm, ws, 2048, 0);
    fragprep_kernel<<<dim3(128), dim3(256), 0, stream>>>(Rm, ws, 512, 1);
    transpose_kernel<<<dim3(512), dim3(256), 0, stream>>>(ws);
    for (int k = 0; k < LL; ++k) {
        exciteR_kernel<<<dim3(512), dim3(256), 0, stream>>>(ws, k);
        exciteM_kernel<<<dim3(512), dim3(256), 0, stream>>>(ws, k);
    }
    exciteO_kernel<<<dim3(1024), dim3(256), 0, stream>>>(ws, Wo, bo, d_out);
}